// Round 2
// baseline (812.023 us; speedup 1.0000x reference)
//
#include <hip/hip_runtime.h>
#include <hip/hip_bf16.h>

constexpr int kB = 8, kN = 256, kD = 16, kHID = 256, kH = 128, kDH = 64, kdh = 32;
constexpr int kBN = kB * kN;          // 2048 rows
constexpr int kP  = kBN * kD;         // 32768 points

__device__ __forceinline__ float b2f(__hip_bfloat16 v) { return __bfloat162float(v); }
__device__ __forceinline__ __hip_bfloat16 f2b(float v) { return __float2bfloat16(v); }

// ---------- Kernel 1: k/v 3-layer tanh MLPs, 4 rows per block ----------
__global__ __launch_bounds__(256) void kv_kernel(
    const float* x,
    const float* k_w0, const float* k_b0,
    const float* k_w1, const float* k_b1,
    const float* k_w2, const float* k_b2,
    const float* v_w0, const float* v_b0,
    const float* v_w1, const float* v_b1,
    const float* v_w2, const float* v_b2,
    __hip_bfloat16* kout, __hip_bfloat16* vout)
{
    const int r0  = blockIdx.x * 4;
    const int tid = threadIdx.x;
    __shared__ float xin[4][kD];
    __shared__ float h0[4][kHID];
    __shared__ float h1[4][kHID];
    if (tid < 64) xin[tid >> 4][tid & 15] = x[(r0 + (tid >> 4)) * kD + (tid & 15)];

    const float* W0[2] = { k_w0, v_w0 };
    const float* B0[2] = { k_b0, v_b0 };
    const float* W1[2] = { k_w1, v_w1 };
    const float* B1[2] = { k_b1, v_b1 };
    const float* W2[2] = { k_w2, v_w2 };
    const float* B2[2] = { k_b2, v_b2 };
    __hip_bfloat16* OUT[2] = { kout, vout };

    for (int path = 0; path < 2; ++path) {
        __syncthreads();   // protects xin (path 0) and h1 reuse (path 1)
        float a[4];
        float bv = B0[path][tid];
        #pragma unroll
        for (int rr = 0; rr < 4; ++rr) a[rr] = bv;
        for (int i = 0; i < kD; ++i) {
            float w = W0[path][i * kHID + tid];
            #pragma unroll
            for (int rr = 0; rr < 4; ++rr) a[rr] += xin[rr][i] * w;
        }
        #pragma unroll
        for (int rr = 0; rr < 4; ++rr) h0[rr][tid] = tanhf(a[rr]);
        __syncthreads();

        bv = B1[path][tid];
        #pragma unroll
        for (int rr = 0; rr < 4; ++rr) a[rr] = bv;
        for (int i = 0; i < kHID; ++i) {
            float w = W1[path][i * kHID + tid];
            #pragma unroll
            for (int rr = 0; rr < 4; ++rr) a[rr] += h0[rr][i] * w;
        }
        #pragma unroll
        for (int rr = 0; rr < 4; ++rr) h1[rr][tid] = tanhf(a[rr]);
        __syncthreads();

        {
            const int u = tid & 127, g = tid >> 7;   // g in {0,1}: rows {2g, 2g+1}
            float b2v = B2[path][u];
            float a0 = b2v, a1 = b2v;
            for (int i = 0; i < kHID; ++i) {
                float w = W2[path][i * kH + u];
                a0 += h1[g * 2][i] * w;
                a1 += h1[g * 2 + 1][i] * w;
            }
            OUT[path][(r0 + g * 2) * kH + u]     = f2b(a0);
            OUT[path][(r0 + g * 2 + 1) * kH + u] = f2b(a1);
        }
    }
}

// ---------- Kernel 2: MADE query net (masks computed analytically), 4 rows/block ----------
__global__ __launch_bounds__(256) void q_kernel(
    const float* x,
    const float* q_w0, const float* q_b0,
    const float* q_w1, const float* q_b1,
    const float* q_w2, const float* q_b2,
    __hip_bfloat16* qout)
{
    const int r0  = blockIdx.x * 4;
    const int tid = threadIdx.x;
    __shared__ float xin[4][kD];
    __shared__ float h0[4][kHID];
    __shared__ float h1[4][kHID];
    if (tid < 64) xin[tid >> 4][tid & 15] = x[(r0 + (tid >> 4)) * kD + (tid & 15)];
    __syncthreads();

    const int jm = tid % 15;   // h_deg(tid) - 1
    float a[4];
    {   // layer 0: mask m0[i][j] = (j%15) >= i
        float bv = q_b0[tid];
        #pragma unroll
        for (int rr = 0; rr < 4; ++rr) a[rr] = bv;
        for (int i = 0; i < kD; ++i) {
            float w = (jm >= i) ? q_w0[i * kHID + tid] : 0.f;
            #pragma unroll
            for (int rr = 0; rr < 4; ++rr) a[rr] += xin[rr][i] * w;
        }
        #pragma unroll
        for (int rr = 0; rr < 4; ++rr) h0[rr][tid] = fmaxf(a[rr], 0.f);
    }
    __syncthreads();
    {   // layer 1: mask m1[i][j] = (j%15) >= (i%15)
        float bv = q_b1[tid];
        #pragma unroll
        for (int rr = 0; rr < 4; ++rr) a[rr] = bv;
        int im = 0;
        for (int i = 0; i < kHID; ++i) {
            float w = (jm >= im) ? q_w1[i * kHID + tid] : 0.f;
            #pragma unroll
            for (int rr = 0; rr < 4; ++rr) a[rr] += h0[rr][i] * w;
            if (++im == 15) im = 0;
        }
        #pragma unroll
        for (int rr = 0; rr < 4; ++rr) h1[rr][tid] = fmaxf(a[rr], 0.f);
    }
    __syncthreads();
    // layer 2: 2048 outputs, mask m2[i][o] = (o>>7) > (i%15)
    for (int kk = 0; kk < 8; ++kk) {
        const int o = kk * 256 + tid;
        const int d = o >> 7;
        float bv = q_b2[o];
        float a2[4];
        #pragma unroll
        for (int rr = 0; rr < 4; ++rr) a2[rr] = bv;
        int im = 0;
        for (int i = 0; i < kHID; ++i) {
            float w = (d > im) ? q_w2[i * (kD * kH) + o] : 0.f;
            #pragma unroll
            for (int rr = 0; rr < 4; ++rr) a2[rr] += h1[rr][i] * w;
            if (++im == 15) im = 0;
        }
        #pragma unroll
        for (int rr = 0; rr < 4; ++rr) qout[(size_t)(r0 + rr) * (kD * kH) + o] = f2b(a2[rr]);
    }
}

// ---------- Kernel 3: diag-masked attention, online softmax. block=(b,d,head), thread=query n ----------
__global__ __launch_bounds__(256) void attn_kernel(
    const __hip_bfloat16* qbuf, const __hip_bfloat16* kbuf, const __hip_bfloat16* vbuf,
    __hip_bfloat16* obuf)
{
    const int blk = blockIdx.x;            // b*64 + d*4 + hd
    const int b  = blk >> 6;
    const int d  = (blk >> 2) & 15;
    const int hd = blk & 3;
    const int n  = threadIdx.x;

    __shared__ float kt[64][kdh];
    __shared__ float vt[64][kdh];

    float q[kdh];
    {
        const __hip_bfloat16* qp = qbuf + (size_t)(b * kN + n) * (kD * kH) + d * kH + hd * kdh;
        #pragma unroll
        for (int c = 0; c < kdh; ++c) q[c] = b2f(qp[c]);
    }
    float mx = -1e30f, l = 0.f;
    float o[kdh];
    #pragma unroll
    for (int c = 0; c < kdh; ++c) o[c] = 0.f;

    for (int t0 = 0; t0 < kN; t0 += 64) {
        __syncthreads();
        for (int idx = n; idx < 64 * kdh; idx += 256) {
            const int ml = idx >> 5, c = idx & 31;
            const int m  = t0 + ml;
            kt[ml][c] = b2f(kbuf[(size_t)(b * kN + m) * kH + hd * kdh + c]);
            vt[ml][c] = b2f(vbuf[(size_t)(b * kN + m) * kH + hd * kdh + c]);
        }
        __syncthreads();
        for (int ml = 0; ml < 64; ++ml) {
            const int m = t0 + ml;
            float s = 0.f;
            #pragma unroll
            for (int c = 0; c < kdh; ++c) s += q[c] * kt[ml][c];
            s *= 0.17677669529663687f;           // 1/sqrt(32)
            if (m == n) s = -1e30f;              // hollow diagonal
            const float nm   = fmaxf(mx, s);
            const float corr = __expf(mx - nm);
            const float p    = __expf(s - nm);
            l = l * corr + p;
            #pragma unroll
            for (int c = 0; c < kdh; ++c) o[c] = o[c] * corr + p * vt[ml][c];
            mx = nm;
        }
    }
    const float inv = 1.f / l;
    __hip_bfloat16* op = obuf + ((size_t)((b * kN + n) * kD + d)) * kH + hd * kdh;
    #pragma unroll
    for (int c = 0; c < kdh; ++c) op[c] = f2b(o[c] * inv);
}

// ---------- Kernel 4: hfeat projection + dimwise MLP with exact JVP. 8 points/block ----------
__global__ __launch_bounds__(256) void dim_kernel(
    const float* t, const float* x,
    const float* p_w, const float* p_b,
    const float* d_w0, const float* d_b0,
    const float* d_w1, const float* d_b1,
    const float* d_w2, const float* d_b2,
    const float* d_w3, const float* d_b3,
    const __hip_bfloat16* obuf, float* out)
{
    const int p0  = blockIdx.x * 8;
    const int tid = threadIdx.x;
    __shared__ float orow[8][kH];
    __shared__ float hf[8][kDH];
    __shared__ float xv[8];
    __shared__ float zA[8][kHID], zdA[8][kHID];
    __shared__ float zB[8][kHID], zdB[8][kHID];
    __shared__ float z3[8][kH],  zd3[8][kH];

    for (int idx = tid; idx < 8 * kH; idx += 256)
        orow[idx >> 7][idx & 127] = b2f(obuf[(size_t)p0 * kH + idx]);
    if (tid < 8) xv[tid] = x[p0 + tid];   // x flat [B,N,D] == point index
    const float tval = t[0];
    __syncthreads();

    {   // hfeat = orow @ p_w + p_b  (64 outs x 8 pts; thread -> (u, {g, g+4}))
        const int u = tid & 63, g = tid >> 6;
        float a0 = p_b[u];
        float a1 = a0;
        for (int c = 0; c < kH; ++c) {
            float w = p_w[c * kDH + u];
            a0 += orow[g][c] * w;
            a1 += orow[g + 4][c] * w;
        }
        hf[g][u] = a0; hf[g + 4][u] = a1;
    }
    __syncthreads();

    {   // layer 0: in = [t, x_d, hf(64)]; tangent enters only via x channel
        float bv = d_b0[tid];
        float wt = d_w0[tid];            // row 0 (t)
        float wx = d_w0[kHID + tid];     // row 1 (x)
        float a[8];
        #pragma unroll
        for (int pp = 0; pp < 8; ++pp) a[pp] = bv + tval * wt + xv[pp] * wx;
        for (int i = 0; i < kDH; ++i) {
            float w = d_w0[(2 + i) * kHID + tid];
            #pragma unroll
            for (int pp = 0; pp < 8; ++pp) a[pp] += hf[pp][i] * w;
        }
        #pragma unroll
        for (int pp = 0; pp < 8; ++pp) {
            float zz = tanhf(a[pp]);
            zA[pp][tid]  = zz;
            zdA[pp][tid] = (1.f - zz * zz) * wx;
        }
    }
    __syncthreads();

    {   // layer 1 (256->256) forward + tangent
        float bv = d_b1[tid];
        float a[8], tt[8];
        #pragma unroll
        for (int pp = 0; pp < 8; ++pp) { a[pp] = bv; tt[pp] = 0.f; }
        for (int i = 0; i < kHID; ++i) {
            float w = d_w1[i * kHID + tid];
            #pragma unroll
            for (int pp = 0; pp < 8; ++pp) {
                a[pp]  += zA[pp][i] * w;
                tt[pp] += zdA[pp][i] * w;
            }
        }
        #pragma unroll
        for (int pp = 0; pp < 8; ++pp) {
            float zz = tanhf(a[pp]);
            zB[pp][tid]  = zz;
            zdB[pp][tid] = (1.f - zz * zz) * tt[pp];
        }
    }
    __syncthreads();

    {   // layer 2 (256->128): thread -> (u, 4 points of group g)
        const int u = tid & 127, g = tid >> 7;
        float bv = d_b2[u];
        float a[4], tt[4];
        #pragma unroll
        for (int qq = 0; qq < 4; ++qq) { a[qq] = bv; tt[qq] = 0.f; }
        for (int i = 0; i < kHID; ++i) {
            float w = d_w2[i * kH + u];
            #pragma unroll
            for (int qq = 0; qq < 4; ++qq) {
                const int pp = g * 4 + qq;
                a[qq]  += zB[pp][i] * w;
                tt[qq] += zdB[pp][i] * w;
            }
        }
        #pragma unroll
        for (int qq = 0; qq < 4; ++qq) {
            const int pp = g * 4 + qq;
            float zz = tanhf(a[qq]);
            z3[pp][u]  = zz;
            zd3[pp][u] = (1.f - zz * zz) * tt[qq];
        }
    }
    __syncthreads();

    {   // layer 3 (128->1) reduce: 8 groups of 32 lanes
        const int pp = tid >> 5, lane = tid & 31;
        float yv = 0.f, jv = 0.f;
        for (int ii = lane; ii < kH; ii += 32) {
            float w = d_w3[ii];
            yv += z3[pp][ii] * w;
            jv += zd3[pp][ii] * w;
        }
        #pragma unroll
        for (int off = 16; off > 0; off >>= 1) {
            yv += __shfl_down(yv, off, 32);
            jv += __shfl_down(jv, off, 32);
        }
        if (lane == 0) {
            const int p = p0 + pp;
            out[p]      = yv + d_b3[0];
            out[kP + p] = jv;
        }
    }
}

extern "C" void kernel_launch(void* const* d_in, const int* in_sizes, int n_in,
                              void* d_out, int out_size, void* d_ws, size_t ws_size,
                              hipStream_t stream)
{
    typedef const float* fp;
    fp t    = (fp)d_in[0];
    fp x    = (fp)d_in[1];
    fp q_w0 = (fp)d_in[2],  q_b0 = (fp)d_in[3];
    fp k_w0 = (fp)d_in[4],  k_b0 = (fp)d_in[5];
    fp v_w0 = (fp)d_in[6],  v_b0 = (fp)d_in[7];
    fp q_w1 = (fp)d_in[8],  q_b1 = (fp)d_in[9];
    fp k_w1 = (fp)d_in[10], k_b1 = (fp)d_in[11];
    fp v_w1 = (fp)d_in[12], v_b1 = (fp)d_in[13];
    fp q_w2 = (fp)d_in[14], q_b2 = (fp)d_in[15];
    fp k_w2 = (fp)d_in[16], k_b2 = (fp)d_in[17];
    fp v_w2 = (fp)d_in[18], v_b2 = (fp)d_in[19];
    fp p_w  = (fp)d_in[20], p_b  = (fp)d_in[21];
    fp d_w0 = (fp)d_in[22], d_b0 = (fp)d_in[23];
    fp d_w1 = (fp)d_in[24], d_b1 = (fp)d_in[25];
    fp d_w2 = (fp)d_in[26], d_b2 = (fp)d_in[27];
    fp d_w3 = (fp)d_in[28], d_b3 = (fp)d_in[29];
    // d_in[30..32] = q_m0/q_m1/q_m2 masks: recomputed analytically in-kernel.

    // bf16 workspace intermediates (~17.8 MB total)
    __hip_bfloat16* ws   = (__hip_bfloat16*)d_ws;
    __hip_bfloat16* kbuf = ws;                                   // [2048][128]
    __hip_bfloat16* vbuf = kbuf + (size_t)kBN * kH;              // [2048][128]
    __hip_bfloat16* qbuf = vbuf + (size_t)kBN * kH;              // [2048][2048]
    __hip_bfloat16* obuf = qbuf + (size_t)kBN * kD * kH;         // [32768][128]

    float* out = (float*)d_out;

    kv_kernel<<<kBN / 4, 256, 0, stream>>>(x,
        k_w0, k_b0, k_w1, k_b1, k_w2, k_b2,
        v_w0, v_b0, v_w1, v_b1, v_w2, v_b2, kbuf, vbuf);
    q_kernel<<<kBN / 4, 256, 0, stream>>>(x, q_w0, q_b0, q_w1, q_b1, q_w2, q_b2, qbuf);
    attn_kernel<<<kB * kD * 4, 256, 0, stream>>>(qbuf, kbuf, vbuf, obuf);
    dim_kernel<<<kP / 8, 256, 0, stream>>>(t, x, p_w, p_b,
        d_w0, d_b0, d_w1, d_b1, d_w2, d_b2, d_w3, d_b3, obuf, out);
}

// Round 3
// 445.270 us; speedup vs baseline: 1.8237x; 1.8237x over previous
//
#include <hip/hip_runtime.h>
#include <hip/hip_bf16.h>

constexpr int kB = 8, kN = 256, kD = 16, kHID = 256, kH = 128, kDH = 64, kdh = 32;
constexpr int kBN = kB * kN;          // 2048 rows
constexpr int kP  = kBN * kD;         // 32768 points

__device__ __forceinline__ float b2f(__hip_bfloat16 v) { return __bfloat162float(v); }
__device__ __forceinline__ __hip_bfloat16 f2b(float v) { return __float2bfloat16(v); }

__device__ __forceinline__ float tanh_fast(float v) {
    // tanh(v) = 1 - 2/(exp(2v)+1); v_exp_f32 + v_rcp_f32. Saturates correctly at +-inf.
    float e = __expf(2.f * v);
    return 1.f - 2.f * __builtin_amdgcn_rcpf(e + 1.f);
}

typedef short s8v  __attribute__((ext_vector_type(8)));   // 8 bf16 = 4 VGPRs
typedef float f4v  __attribute__((ext_vector_type(4)));
#define MFMA(a, b, c) __builtin_amdgcn_mfma_f32_16x16x32_bf16((a), (b), (c), 0, 0, 0)

// ---------- Prep A: swizzle dimwise/proj weights into MFMA B-fragment layout (bf16) ----------
// frag[((kt*NT+nt)*64 + lane)*8 + j] = W[kt*32 + (lane>>4)*8 + j][nt*16 + (lane&15)]
__global__ __launch_bounds__(256) void prep_frag(
    const float* p_w, const float* d_w0, const float* d_w1, const float* d_w2,
    __hip_bfloat16* pwf, __hip_bfloat16* w0f, __hip_bfloat16* w1f, __hip_bfloat16* w2f)
{
    const int tile = blockIdx.x * 4 + (threadIdx.x >> 6);
    const int lane = threadIdx.x & 63;
    const float* src; __hip_bfloat16* dst; int N, NT, local;
    if (tile < 16)       { src = p_w;           dst = pwf; N = 64;  NT = 4;  local = tile; }
    else if (tile < 48)  { src = d_w0 + 2*256;  dst = w0f; N = 256; NT = 16; local = tile - 16; }
    else if (tile < 176) { src = d_w1;          dst = w1f; N = 256; NT = 16; local = tile - 48; }
    else                 { src = d_w2;          dst = w2f; N = 128; NT = 8;  local = tile - 176; }
    const int kt = local / NT, nt = local % NT;
    const int krow = kt * 32 + (lane >> 4) * 8;
    const int col  = nt * 16 + (lane & 15);
    __hip_bfloat16* o = dst + ((size_t)local * 64 + lane) * 8;
    #pragma unroll
    for (int j = 0; j < 8; ++j) o[j] = f2b(src[(size_t)(krow + j) * N + col]);
}

// ---------- Prep B: premultiply MADE masks into q weights (fp32) ----------
__global__ __launch_bounds__(256) void prep_qmask(
    const float* q_w0, const float* q_w1, const float* q_w2,
    float* qm0, float* qm1, float* qm2)
{
    const int e = blockIdx.x * 256 + threadIdx.x;
    if (e < 4096) {
        const int i = e >> 8, j = e & 255;
        qm0[e] = ((j % 15) >= i) ? q_w0[e] : 0.f;
    } else if (e < 4096 + 65536) {
        const int e1 = e - 4096; const int i = e1 >> 8, j = e1 & 255;
        qm1[e1] = ((j % 15) >= (i % 15)) ? q_w1[e1] : 0.f;
    } else {
        const int e2 = e - 4096 - 65536;            // < 524288
        const int i = e2 >> 11, o = e2 & 2047;
        qm2[e2] = ((o >> 7) > (i % 15)) ? q_w2[e2] : 0.f;
    }
}

// ---------- Kernel 1: k/v 3-layer tanh MLPs, 4 rows per block ----------
__global__ __launch_bounds__(256) void kv_kernel(
    const float* x,
    const float* k_w0, const float* k_b0,
    const float* k_w1, const float* k_b1,
    const float* k_w2, const float* k_b2,
    const float* v_w0, const float* v_b0,
    const float* v_w1, const float* v_b1,
    const float* v_w2, const float* v_b2,
    __hip_bfloat16* kout, __hip_bfloat16* vout)
{
    const int r0  = blockIdx.x * 4;
    const int tid = threadIdx.x;
    __shared__ float xin[4][kD];
    __shared__ float h0[4][kHID];
    __shared__ float h1[4][kHID];
    if (tid < 64) xin[tid >> 4][tid & 15] = x[(r0 + (tid >> 4)) * kD + (tid & 15)];

    const float* W0[2] = { k_w0, v_w0 };
    const float* B0[2] = { k_b0, v_b0 };
    const float* W1[2] = { k_w1, v_w1 };
    const float* B1[2] = { k_b1, v_b1 };
    const float* W2[2] = { k_w2, v_w2 };
    const float* B2[2] = { k_b2, v_b2 };
    __hip_bfloat16* OUT[2] = { kout, vout };

    for (int path = 0; path < 2; ++path) {
        __syncthreads();
        float a[4];
        float bv = B0[path][tid];
        #pragma unroll
        for (int rr = 0; rr < 4; ++rr) a[rr] = bv;
        for (int i = 0; i < kD; ++i) {
            float w = W0[path][i * kHID + tid];
            #pragma unroll
            for (int rr = 0; rr < 4; ++rr) a[rr] += xin[rr][i] * w;
        }
        #pragma unroll
        for (int rr = 0; rr < 4; ++rr) h0[rr][tid] = tanh_fast(a[rr]);
        __syncthreads();

        bv = B1[path][tid];
        #pragma unroll
        for (int rr = 0; rr < 4; ++rr) a[rr] = bv;
        for (int i = 0; i < kHID; ++i) {
            float w = W1[path][i * kHID + tid];
            #pragma unroll
            for (int rr = 0; rr < 4; ++rr) a[rr] += h0[rr][i] * w;
        }
        #pragma unroll
        for (int rr = 0; rr < 4; ++rr) h1[rr][tid] = tanh_fast(a[rr]);
        __syncthreads();

        {
            const int u = tid & 127, g = tid >> 7;
            float b2v = B2[path][u];
            float a0 = b2v, a1 = b2v;
            for (int i = 0; i < kHID; ++i) {
                float w = W2[path][i * kH + u];
                a0 += h1[g * 2][i] * w;
                a1 += h1[g * 2 + 1][i] * w;
            }
            OUT[path][(r0 + g * 2) * kH + u]     = f2b(a0);
            OUT[path][(r0 + g * 2 + 1) * kH + u] = f2b(a1);
        }
    }
}

// ---------- Kernel 2: MADE query net with premasked weights, 4 rows/block ----------
__global__ __launch_bounds__(256) void q_kernel(
    const float* x,
    const float* qm0, const float* q_b0,
    const float* qm1, const float* q_b1,
    const float* qm2, const float* q_b2,
    __hip_bfloat16* qout)
{
    const int r0  = blockIdx.x * 4;
    const int tid = threadIdx.x;
    __shared__ float xin[4][kD];
    __shared__ float h0[4][kHID];
    __shared__ float h1[4][kHID];
    if (tid < 64) xin[tid >> 4][tid & 15] = x[(r0 + (tid >> 4)) * kD + (tid & 15)];
    __syncthreads();

    float a[4];
    {
        float bv = q_b0[tid];
        #pragma unroll
        for (int rr = 0; rr < 4; ++rr) a[rr] = bv;
        for (int i = 0; i < kD; ++i) {
            float w = qm0[i * kHID + tid];
            #pragma unroll
            for (int rr = 0; rr < 4; ++rr) a[rr] += xin[rr][i] * w;
        }
        #pragma unroll
        for (int rr = 0; rr < 4; ++rr) h0[rr][tid] = fmaxf(a[rr], 0.f);
    }
    __syncthreads();
    {
        float bv = q_b1[tid];
        #pragma unroll
        for (int rr = 0; rr < 4; ++rr) a[rr] = bv;
        for (int i = 0; i < kHID; ++i) {
            float w = qm1[i * kHID + tid];
            #pragma unroll
            for (int rr = 0; rr < 4; ++rr) a[rr] += h0[rr][i] * w;
        }
        #pragma unroll
        for (int rr = 0; rr < 4; ++rr) h1[rr][tid] = fmaxf(a[rr], 0.f);
    }
    __syncthreads();
    for (int kk = 0; kk < 8; ++kk) {
        const int o = kk * 256 + tid;
        float bv = q_b2[o];
        float a2[4];
        #pragma unroll
        for (int rr = 0; rr < 4; ++rr) a2[rr] = bv;
        for (int i = 0; i < kHID; ++i) {
            float w = qm2[i * (kD * kH) + o];
            #pragma unroll
            for (int rr = 0; rr < 4; ++rr) a2[rr] += h1[rr][i] * w;
        }
        #pragma unroll
        for (int rr = 0; rr < 4; ++rr) qout[(size_t)(r0 + rr) * (kD * kH) + o] = f2b(a2[rr]);
    }
}

// ---------- Kernel 3: diag-masked attention, online softmax ----------
__global__ __launch_bounds__(256) void attn_kernel(
    const __hip_bfloat16* qbuf, const __hip_bfloat16* kbuf, const __hip_bfloat16* vbuf,
    __hip_bfloat16* obuf)
{
    const int blk = blockIdx.x;            // b*64 + d*4 + hd
    const int b  = blk >> 6;
    const int d  = (blk >> 2) & 15;
    const int hd = blk & 3;
    const int n  = threadIdx.x;

    __shared__ float kt[64][kdh];
    __shared__ float vt[64][kdh];

    float q[kdh];
    {
        const __hip_bfloat16* qp = qbuf + (size_t)(b * kN + n) * (kD * kH) + d * kH + hd * kdh;
        #pragma unroll
        for (int c = 0; c < kdh; ++c) q[c] = b2f(qp[c]);
    }
    float mx = -1e30f, l = 0.f;
    float o[kdh];
    #pragma unroll
    for (int c = 0; c < kdh; ++c) o[c] = 0.f;

    for (int t0 = 0; t0 < kN; t0 += 64) {
        __syncthreads();
        for (int idx = n; idx < 64 * kdh; idx += 256) {
            const int ml = idx >> 5, c = idx & 31;
            const int m  = t0 + ml;
            kt[ml][c] = b2f(kbuf[(size_t)(b * kN + m) * kH + hd * kdh + c]);
            vt[ml][c] = b2f(vbuf[(size_t)(b * kN + m) * kH + hd * kdh + c]);
        }
        __syncthreads();
        for (int ml = 0; ml < 64; ++ml) {
            const int m = t0 + ml;
            float s = 0.f;
            #pragma unroll
            for (int c = 0; c < kdh; ++c) s += q[c] * kt[ml][c];
            s *= 0.17677669529663687f;           // 1/sqrt(32)
            if (m == n) s = -1e30f;
            const float nm   = fmaxf(mx, s);
            const float corr = __expf(mx - nm);
            const float p    = __expf(s - nm);
            l = l * corr + p;
            #pragma unroll
            for (int c = 0; c < kdh; ++c) o[c] = o[c] * corr + p * vt[ml][c];
            mx = nm;
        }
    }
    const float inv = 1.f / l;
    __hip_bfloat16* op = obuf + ((size_t)((b * kN + n) * kD + d)) * kH + hd * kdh;
    #pragma unroll
    for (int c = 0; c < kdh; ++c) op[c] = f2b(o[c] * inv);
}

// ---------- Kernel 4: MFMA dimwise net. 32 points/block, fwd+tangent as M=64 ----------
__global__ __launch_bounds__(256) void dim_kernel(
    const float* t, const float* x,
    const float* p_b, const float* d_w0, const float* d_b0,
    const float* d_b1, const float* d_b2, const float* d_w3, const float* d_b3,
    const __hip_bfloat16* pwf, const __hip_bfloat16* w0f,
    const __hip_bfloat16* w1f, const __hip_bfloat16* w2f,
    const __hip_bfloat16* obuf, float* out)
{
    constexpr int SA = 264;   // 256 + 8 bf16 pad (rows 16B-aligned, 528B stride)
    constexpr int SO = 136;   // 128 + 8
    constexpr int SH = 72;    // 64 + 8
    __shared__ __hip_bfloat16 bufA[64 * SA];
    __shared__ __hip_bfloat16 bufB[64 * SA];
    __shared__ float xvs[32];

    const int tid  = threadIdx.x;
    const int wv   = tid >> 6, lane = tid & 63;
    const int lx   = lane & 15, quad = lane >> 4;
    const int p0   = blockIdx.x * 32;
    const float tval = t[0];

    // A-fragment from LDS row-major buf: A[m0+lx][k0 + quad*8 + j]
    auto ldA = [&](const __hip_bfloat16* buf, int stride, int m0, int k0) -> s8v {
        return *(const s8v*)(buf + (m0 + lx) * stride + k0 + quad * 8);
    };
    // B-fragment from pre-swizzled global weights
    auto ldBf = [&](const __hip_bfloat16* wf, int NT, int kt, int nt) -> s8v {
        return *(const s8v*)(wf + (((size_t)(kt * NT + nt) * 64 + lane) << 3));
    };

    // ---- stage: obuf rows (32 x 128 bf16) -> bufA (stride SO); x values ----
    for (int idx = tid; idx < 512; idx += 256) {
        const int row = idx >> 4, ch = idx & 15;
        *(f4v*)(bufA + row * SO + ch * 8) = *(const f4v*)(obuf + (size_t)(p0 + row) * kH + ch * 8);
    }
    if (tid < 32) xvs[tid] = x[p0 + tid];
    __syncthreads();

    // ---- hfeat = orow @ p_w + p_b : M=32, N=64, K=128. wave -> 1 N-tile, 2 M-tiles ----
    {
        f4v acc0 = {}, acc1 = {};
        #pragma unroll
        for (int ktile = 0; ktile < 4; ++ktile) {
            s8v b  = ldBf(pwf, 4, ktile, wv);
            s8v a0 = ldA(bufA, SO, 0,  ktile * 32);
            s8v a1 = ldA(bufA, SO, 16, ktile * 32);
            acc0 = MFMA(a0, b, acc0);
            acc1 = MFMA(a1, b, acc1);
        }
        const int n = wv * 16 + lx;
        const float bb = p_b[n];
        #pragma unroll
        for (int r = 0; r < 4; ++r) {
            bufB[(quad * 4 + r) * SH + n]        = f2b(acc0[r] + bb);
            bufB[(16 + quad * 4 + r) * SH + n]   = f2b(acc1[r] + bb);
        }
    }
    __syncthreads();

    // ---- layer0: zA = tanh(hf@w0[2:] + b0 + t*w0[0] + x*w0[1]); zdA = (1-zA^2)*w0[1] ----
    // M=32, N=256, K=64. wave -> 4 N-tiles, 2 M-tiles
    {
        f4v acc[4][2] = {};
        #pragma unroll
        for (int ktile = 0; ktile < 2; ++ktile) {
            s8v a0 = ldA(bufB, SH, 0,  ktile * 32);
            s8v a1 = ldA(bufB, SH, 16, ktile * 32);
            #pragma unroll
            for (int j = 0; j < 4; ++j) {
                s8v b = ldBf(w0f, 16, ktile, wv * 4 + j);
                acc[j][0] = MFMA(a0, b, acc[j][0]);
                acc[j][1] = MFMA(a1, b, acc[j][1]);
            }
        }
        #pragma unroll
        for (int j = 0; j < 4; ++j) {
            const int n = (wv * 4 + j) * 16 + lx;
            const float base = d_b0[n] + tval * d_w0[n];
            const float wx   = d_w0[256 + n];
            #pragma unroll
            for (int mt = 0; mt < 2; ++mt)
            #pragma unroll
            for (int r = 0; r < 4; ++r) {
                const int m = mt * 16 + quad * 4 + r;
                const float z = tanh_fast(acc[j][mt][r] + base + xvs[m] * wx);
                bufA[m * SA + n]        = f2b(z);
                bufA[(m + 32) * SA + n] = f2b((1.f - z * z) * wx);
            }
        }
    }
    __syncthreads();

    // ---- layer1: M=64 (fwd rows 0-31, tgt rows 32-63), N=256, K=256 ----
    {
        f4v acc[4][4] = {};
        #pragma unroll
        for (int ktile = 0; ktile < 8; ++ktile) {
            s8v a[4];
            #pragma unroll
            for (int mt = 0; mt < 4; ++mt) a[mt] = ldA(bufA, SA, mt * 16, ktile * 32);
            #pragma unroll
            for (int j = 0; j < 4; ++j) {
                s8v b = ldBf(w1f, 16, ktile, wv * 4 + j);
                #pragma unroll
                for (int mt = 0; mt < 4; ++mt) acc[j][mt] = MFMA(a[mt], b, acc[j][mt]);
            }
        }
        #pragma unroll
        for (int j = 0; j < 4; ++j) {
            const int n = (wv * 4 + j) * 16 + lx;
            const float b1 = d_b1[n];
            #pragma unroll
            for (int mt = 0; mt < 2; ++mt)
            #pragma unroll
            for (int r = 0; r < 4; ++r) {
                const int m = mt * 16 + quad * 4 + r;
                const float z  = tanh_fast(acc[j][mt][r] + b1);
                const float zd = (1.f - z * z) * acc[j][mt + 2][r];
                bufB[m * SA + n]        = f2b(z);
                bufB[(m + 32) * SA + n] = f2b(zd);
            }
        }
    }
    __syncthreads();

    // ---- layer2: M=64, N=128, K=256 ----
    {
        f4v acc[2][4] = {};
        #pragma unroll
        for (int ktile = 0; ktile < 8; ++ktile) {
            s8v a[4];
            #pragma unroll
            for (int mt = 0; mt < 4; ++mt) a[mt] = ldA(bufB, SA, mt * 16, ktile * 32);
            #pragma unroll
            for (int j = 0; j < 2; ++j) {
                s8v b = ldBf(w2f, 8, ktile, wv * 2 + j);
                #pragma unroll
                for (int mt = 0; mt < 4; ++mt) acc[j][mt] = MFMA(a[mt], b, acc[j][mt]);
            }
        }
        #pragma unroll
        for (int j = 0; j < 2; ++j) {
            const int n = (wv * 2 + j) * 16 + lx;
            const float b2 = d_b2[n];
            #pragma unroll
            for (int mt = 0; mt < 2; ++mt)
            #pragma unroll
            for (int r = 0; r < 4; ++r) {
                const int m = mt * 16 + quad * 4 + r;
                const float z  = tanh_fast(acc[j][mt][r] + b2);
                const float zd = (1.f - z * z) * acc[j][mt + 2][r];
                bufA[m * SO + n]        = f2b(z);
                bufA[(m + 32) * SO + n] = f2b(zd);
            }
        }
    }
    __syncthreads();

    // ---- layer3: y = z3@w3 + b3 ; jac = zd3@w3. 8 threads per point ----
    {
        const int p = tid >> 3, s = tid & 7;
        float yv = 0.f, jv = 0.f;
        #pragma unroll
        for (int i = 0; i < 16; ++i) {
            const int n = s + i * 8;
            const float w = d_w3[n];
            yv += b2f(bufA[p * SO + n]) * w;
            jv += b2f(bufA[(p + 32) * SO + n]) * w;
        }
        #pragma unroll
        for (int off = 4; off > 0; off >>= 1) {
            yv += __shfl_down(yv, off, 8);
            jv += __shfl_down(jv, off, 8);
        }
        if (s == 0) {
            out[p0 + p]      = yv + d_b3[0];
            out[kP + p0 + p] = jv;
        }
    }
}

extern "C" void kernel_launch(void* const* d_in, const int* in_sizes, int n_in,
                              void* d_out, int out_size, void* d_ws, size_t ws_size,
                              hipStream_t stream)
{
    typedef const float* fp;
    fp t    = (fp)d_in[0];
    fp x    = (fp)d_in[1];
    fp q_w0 = (fp)d_in[2],  q_b0 = (fp)d_in[3];
    fp k_w0 = (fp)d_in[4],  k_b0 = (fp)d_in[5];
    fp v_w0 = (fp)d_in[6],  v_b0 = (fp)d_in[7];
    fp q_w1 = (fp)d_in[8],  q_b1 = (fp)d_in[9];
    fp k_w1 = (fp)d_in[10], k_b1 = (fp)d_in[11];
    fp v_w1 = (fp)d_in[12], v_b1 = (fp)d_in[13];
    fp q_w2 = (fp)d_in[14], q_b2 = (fp)d_in[15];
    fp k_w2 = (fp)d_in[16], k_b2 = (fp)d_in[17];
    fp v_w2 = (fp)d_in[18], v_b2 = (fp)d_in[19];
    fp p_w  = (fp)d_in[20], p_b  = (fp)d_in[21];
    fp d_w0 = (fp)d_in[22], d_b0 = (fp)d_in[23];
    fp d_w1 = (fp)d_in[24], d_b1 = (fp)d_in[25];
    fp d_w2 = (fp)d_in[26], d_b2 = (fp)d_in[27];
    fp d_w3 = (fp)d_in[28], d_b3 = (fp)d_in[29];
    // d_in[30..32] = q_m0/q_m1/q_m2 masks: applied analytically in prep_qmask.

    // workspace layout (~19.5 MB)
    __hip_bfloat16* wsb  = (__hip_bfloat16*)d_ws;
    __hip_bfloat16* kbuf = wsb;                                  // 2048*128
    __hip_bfloat16* vbuf = kbuf + (size_t)kBN * kH;              // 2048*128
    __hip_bfloat16* qbuf = vbuf + (size_t)kBN * kH;              // 2048*2048
    __hip_bfloat16* obuf = qbuf + (size_t)kBN * kD * kH;         // 32768*128
    __hip_bfloat16* pwf  = obuf + (size_t)kP * kH;               // 8192
    __hip_bfloat16* w0f  = pwf + 8192;                           // 16384
    __hip_bfloat16* w1f  = w0f + 16384;                          // 65536
    __hip_bfloat16* w2f  = w1f + 65536;                          // 32768
    float* qm0 = (float*)(w2f + 32768);                          // 4096
    float* qm1 = qm0 + 4096;                                     // 65536
    float* qm2 = qm1 + 65536;                                    // 524288

    float* out = (float*)d_out;

    prep_frag<<<60, 256, 0, stream>>>(p_w, d_w0, d_w1, d_w2, pwf, w0f, w1f, w2f);
    prep_qmask<<<2320, 256, 0, stream>>>(q_w0, q_w1, q_w2, qm0, qm1, qm2);
    kv_kernel<<<kBN / 4, 256, 0, stream>>>(x,
        k_w0, k_b0, k_w1, k_b1, k_w2, k_b2,
        v_w0, v_b0, v_w1, v_b1, v_w2, v_b2, kbuf, vbuf);
    q_kernel<<<kBN / 4, 256, 0, stream>>>(x, qm0, q_b0, qm1, q_b1, qm2, q_b2, qbuf);
    attn_kernel<<<kB * kD * 4, 256, 0, stream>>>(qbuf, kbuf, vbuf, obuf);
    dim_kernel<<<kP / 32, 256, 0, stream>>>(t, x, p_b, d_w0, d_b0, d_b1, d_b2, d_w3, d_b3,
        pwf, w0f, w1f, w2f, obuf, out);
}

// Round 4
// 343.247 us; speedup vs baseline: 2.3657x; 1.2972x over previous
//
#include <hip/hip_runtime.h>
#include <hip/hip_bf16.h>

constexpr int kB = 8, kN = 256, kD = 16, kHID = 256, kH = 128, kDH = 64, kdh = 32;
constexpr int kBN = kB * kN;          // 2048 rows
constexpr int kP  = kBN * kD;         // 32768 points

__device__ __forceinline__ float b2f(__hip_bfloat16 v) { return __bfloat162float(v); }
__device__ __forceinline__ __hip_bfloat16 f2b(float v) { return __float2bfloat16(v); }
__device__ __forceinline__ unsigned short f2bs(float v) {
    __hip_bfloat16 h = __float2bfloat16(v);
    return *(unsigned short*)&h;
}
__device__ __forceinline__ float bs2f(unsigned short s) {
    unsigned int u = ((unsigned int)s) << 16;
    return *(float*)&u;
}

__device__ __forceinline__ float tanh_fast(float v) {
    float e = __expf(2.f * v);
    return 1.f - 2.f * __builtin_amdgcn_rcpf(e + 1.f);
}

typedef short s8v  __attribute__((ext_vector_type(8)));   // 8 bf16 = 4 VGPRs
typedef float f4v  __attribute__((ext_vector_type(4)));
#define MFMA(a, b, c) __builtin_amdgcn_mfma_f32_16x16x32_bf16((a), (b), (c), 0, 0, 0)

// ---------- Prep A: swizzle dimwise/proj weights into MFMA B-fragment layout (bf16) ----------
__global__ __launch_bounds__(256) void prep_frag(
    const float* p_w, const float* d_w0, const float* d_w1, const float* d_w2,
    __hip_bfloat16* pwf, __hip_bfloat16* w0f, __hip_bfloat16* w1f, __hip_bfloat16* w2f)
{
    const int tile = blockIdx.x * 4 + (threadIdx.x >> 6);
    const int lane = threadIdx.x & 63;
    const float* src; __hip_bfloat16* dst; int N, NT, local;
    if (tile < 16)       { src = p_w;           dst = pwf; N = 64;  NT = 4;  local = tile; }
    else if (tile < 48)  { src = d_w0 + 2*256;  dst = w0f; N = 256; NT = 16; local = tile - 16; }
    else if (tile < 176) { src = d_w1;          dst = w1f; N = 256; NT = 16; local = tile - 48; }
    else                 { src = d_w2;          dst = w2f; N = 128; NT = 8;  local = tile - 176; }
    const int kt = local / NT, nt = local % NT;
    const int krow = kt * 32 + (lane >> 4) * 8;
    const int col  = nt * 16 + (lane & 15);
    __hip_bfloat16* o = dst + ((size_t)local * 64 + lane) * 8;
    #pragma unroll
    for (int j = 0; j < 8; ++j) o[j] = f2b(src[(size_t)(krow + j) * N + col]);
}

// ---------- Prep B: premultiply MADE masks into q weights (fp32) ----------
__global__ __launch_bounds__(256) void prep_qmask(
    const float* q_w0, const float* q_w1, const float* q_w2,
    float* qm0, float* qm1, float* qm2)
{
    const int e = blockIdx.x * 256 + threadIdx.x;
    if (e < 4096) {
        const int i = e >> 8, j = e & 255;
        qm0[e] = ((j % 15) >= i) ? q_w0[e] : 0.f;
    } else if (e < 4096 + 65536) {
        const int e1 = e - 4096; const int i = e1 >> 8, j = e1 & 255;
        qm1[e1] = ((j % 15) >= (i % 15)) ? q_w1[e1] : 0.f;
    } else {
        const int e2 = e - 4096 - 65536;            // < 524288
        const int i = e2 >> 11, o = e2 & 2047;
        qm2[e2] = ((o >> 7) > (i % 15)) ? q_w2[e2] : 0.f;
    }
}

// ---------- Kernel 1: k/v 3-layer tanh MLPs, 4 rows per block ----------
__global__ __launch_bounds__(256) void kv_kernel(
    const float* x,
    const float* k_w0, const float* k_b0,
    const float* k_w1, const float* k_b1,
    const float* k_w2, const float* k_b2,
    const float* v_w0, const float* v_b0,
    const float* v_w1, const float* v_b1,
    const float* v_w2, const float* v_b2,
    __hip_bfloat16* kout, __hip_bfloat16* vout)
{
    const int r0  = blockIdx.x * 4;
    const int tid = threadIdx.x;
    __shared__ float xin[4][kD];
    __shared__ float h0[4][kHID];
    __shared__ float h1[4][kHID];
    if (tid < 64) xin[tid >> 4][tid & 15] = x[(r0 + (tid >> 4)) * kD + (tid & 15)];

    const float* W0[2] = { k_w0, v_w0 };
    const float* B0[2] = { k_b0, v_b0 };
    const float* W1[2] = { k_w1, v_w1 };
    const float* B1[2] = { k_b1, v_b1 };
    const float* W2[2] = { k_w2, v_w2 };
    const float* B2[2] = { k_b2, v_b2 };
    __hip_bfloat16* OUT[2] = { kout, vout };

    for (int path = 0; path < 2; ++path) {
        __syncthreads();
        float a[4];
        float bv = B0[path][tid];
        #pragma unroll
        for (int rr = 0; rr < 4; ++rr) a[rr] = bv;
        for (int i = 0; i < kD; ++i) {
            float w = W0[path][i * kHID + tid];
            #pragma unroll
            for (int rr = 0; rr < 4; ++rr) a[rr] += xin[rr][i] * w;
        }
        #pragma unroll
        for (int rr = 0; rr < 4; ++rr) h0[rr][tid] = tanh_fast(a[rr]);
        __syncthreads();

        bv = B1[path][tid];
        #pragma unroll
        for (int rr = 0; rr < 4; ++rr) a[rr] = bv;
        for (int i = 0; i < kHID; ++i) {
            float w = W1[path][i * kHID + tid];
            #pragma unroll
            for (int rr = 0; rr < 4; ++rr) a[rr] += h0[rr][i] * w;
        }
        #pragma unroll
        for (int rr = 0; rr < 4; ++rr) h1[rr][tid] = tanh_fast(a[rr]);
        __syncthreads();

        {
            const int u = tid & 127, g = tid >> 7;
            float b2v = B2[path][u];
            float a0 = b2v, a1 = b2v;
            for (int i = 0; i < kHID; ++i) {
                float w = W2[path][i * kH + u];
                a0 += h1[g * 2][i] * w;
                a1 += h1[g * 2 + 1][i] * w;
            }
            OUT[path][(r0 + g * 2) * kH + u]     = f2b(a0);
            OUT[path][(r0 + g * 2 + 1) * kH + u] = f2b(a1);
        }
    }
}

// ---------- Kernel 2: MADE query net with premasked weights, 4 rows/block ----------
__global__ __launch_bounds__(256) void q_kernel(
    const float* x,
    const float* qm0, const float* q_b0,
    const float* qm1, const float* q_b1,
    const float* qm2, const float* q_b2,
    __hip_bfloat16* qout)
{
    const int r0  = blockIdx.x * 4;
    const int tid = threadIdx.x;
    __shared__ float xin[4][kD];
    __shared__ float h0[4][kHID];
    __shared__ float h1[4][kHID];
    if (tid < 64) xin[tid >> 4][tid & 15] = x[(r0 + (tid >> 4)) * kD + (tid & 15)];
    __syncthreads();

    float a[4];
    {
        float bv = q_b0[tid];
        #pragma unroll
        for (int rr = 0; rr < 4; ++rr) a[rr] = bv;
        for (int i = 0; i < kD; ++i) {
            float w = qm0[i * kHID + tid];
            #pragma unroll
            for (int rr = 0; rr < 4; ++rr) a[rr] += xin[rr][i] * w;
        }
        #pragma unroll
        for (int rr = 0; rr < 4; ++rr) h0[rr][tid] = fmaxf(a[rr], 0.f);
    }
    __syncthreads();
    {
        float bv = q_b1[tid];
        #pragma unroll
        for (int rr = 0; rr < 4; ++rr) a[rr] = bv;
        for (int i = 0; i < kHID; ++i) {
            float w = qm1[i * kHID + tid];
            #pragma unroll
            for (int rr = 0; rr < 4; ++rr) a[rr] += h0[rr][i] * w;
        }
        #pragma unroll
        for (int rr = 0; rr < 4; ++rr) h1[rr][tid] = fmaxf(a[rr], 0.f);
    }
    __syncthreads();
    for (int kk = 0; kk < 8; ++kk) {
        const int o = kk * 256 + tid;
        float bv = q_b2[o];
        float a2[4];
        #pragma unroll
        for (int rr = 0; rr < 4; ++rr) a2[rr] = bv;
        for (int i = 0; i < kHID; ++i) {
            float w = qm2[i * (kD * kH) + o];
            #pragma unroll
            for (int rr = 0; rr < 4; ++rr) a2[rr] += h1[rr][i] * w;
        }
        #pragma unroll
        for (int rr = 0; rr < 4; ++rr) qout[(size_t)(r0 + rr) * (kD * kH) + o] = f2b(a2[rr]);
    }
}

// ---------- Kernel 3: MFMA attention. 1 wave/block, block=(b,d,hd,qw), 64 queries/wave ----------
// S^T = K @ Q^T via mfma (A=K tile, B=Q^T tile): C rows = keys (4 consecutive per lane),
// cols = queries (lx). Softmax over keys: in-lane over 64 regs + shfl_xor 16/32.
// P -> wave-private LDS in A-layout (packed b64 writes), split hi/lo bf16 for accuracy.
__global__ __launch_bounds__(64, 2) void attn_kernel(
    const __hip_bfloat16* qbuf, const __hip_bfloat16* kbuf, const __hip_bfloat16* vbuf,
    __hip_bfloat16* obuf)
{
    constexpr int SP = 264;                       // P row stride (elems), 16B-aligned rows
    __shared__ short Pl[16 * SP];

    const int blk = blockIdx.x;                   // b*256 + d*16 + hd*4 + qw
    const int qw = blk & 3;
    const int hd = (blk >> 2) & 3;
    const int d  = (blk >> 4) & 15;
    const int b  = blk >> 8;

    const int lane = threadIdx.x;
    const int lx = lane & 15, quad = lane >> 4;

    const short* kb = (const short*)kbuf;
    const short* vb = (const short*)vbuf;
    const short* qb = (const short*)qbuf;

    // ---- hoist K fragments: A[m=key][k=ch]; lane holds K[mt*16+lx][quad*8+j] ----
    s8v kfrag[16];
    #pragma unroll
    for (int mt = 0; mt < 16; ++mt)
        kfrag[mt] = *(const s8v*)(kb + (size_t)(b * 256 + mt * 16 + lx) * 128 + hd * 32 + quad * 8);

    // ---- hoist V fragments: B[k=key][n=ch]; lane holds V[kt*32+quad*8+j][ntv*16+lx] ----
    s8v vfrag[2][8];
    #pragma unroll
    for (int ntv = 0; ntv < 2; ++ntv)
    #pragma unroll
    for (int kt = 0; kt < 8; ++kt) {
        s8v v;
        #pragma unroll
        for (int j = 0; j < 8; ++j)
            v[j] = vb[(size_t)(b * 256 + kt * 32 + quad * 8 + j) * 128 + hd * 32 + ntv * 16 + lx];
        vfrag[ntv][kt] = v;
    }

    const float scale = 0.17677669529663687f;     // 1/sqrt(32)

    for (int mi = 0; mi < 4; ++mi) {
        const int q0 = qw * 64 + mi * 16;

        // Q^T B-fragment: B[k=ch][n=query]; lane holds Q[q0+lx][quad*8+j]
        s8v qfrag = *(const s8v*)(qb + (size_t)(b * 256 + q0 + lx) * 2048 + d * 128 + hd * 32 + quad * 8);

        f4v acc[16];
        #pragma unroll
        for (int mt = 0; mt < 16; ++mt) acc[mt] = f4v{0.f, 0.f, 0.f, 0.f};
        #pragma unroll
        for (int mt = 0; mt < 16; ++mt) acc[mt] = MFMA(kfrag[mt], qfrag, acc[mt]);

        // mask diagonal + row(=query) max
        const int qg = q0 + lx;                   // this lane's query (column)
        float mx = -3.0e38f;
        #pragma unroll
        for (int mt = 0; mt < 16; ++mt)
        #pragma unroll
        for (int r = 0; r < 4; ++r) {
            const int key = mt * 16 + quad * 4 + r;
            float s = (key == qg) ? -3.0e38f : acc[mt][r];
            acc[mt][r] = s;
            mx = fmaxf(mx, s);
        }
        mx = fmaxf(mx, __shfl_xor(mx, 16, 64));
        mx = fmaxf(mx, __shfl_xor(mx, 32, 64));

        // exp + sum
        float l = 0.f;
        #pragma unroll
        for (int mt = 0; mt < 16; ++mt)
        #pragma unroll
        for (int r = 0; r < 4; ++r) {
            float p = __expf((acc[mt][r] - mx) * scale);
            acc[mt][r] = p;
            l += p;
        }
        l += __shfl_xor(l, 16, 64);
        l += __shfl_xor(l, 32, 64);

        // ---- write P_hi (bf16) to LDS in A-layout: Pl[query=lx][key], keep lo residual in acc ----
        #pragma unroll
        for (int mt = 0; mt < 16; ++mt) {
            unsigned short h0 = f2bs(acc[mt][0]);
            unsigned short h1 = f2bs(acc[mt][1]);
            unsigned short h2 = f2bs(acc[mt][2]);
            unsigned short h3 = f2bs(acc[mt][3]);
            uint2 w;
            w.x = (unsigned int)h0 | ((unsigned int)h1 << 16);
            w.y = (unsigned int)h2 | ((unsigned int)h3 << 16);
            *(uint2*)(Pl + lx * SP + mt * 16 + quad * 4) = w;
            acc[mt][0] -= bs2f(h0);
            acc[mt][1] -= bs2f(h1);
            acc[mt][2] -= bs2f(h2);
            acc[mt][3] -= bs2f(h3);
        }
        __asm__ volatile("s_waitcnt lgkmcnt(0)" ::: "memory");

        // ---- PV pass (hi): A[m=query][k=key] from Pl, B=V frags ----
        f4v av[2] = { f4v{0.f,0.f,0.f,0.f}, f4v{0.f,0.f,0.f,0.f} };
        #pragma unroll
        for (int kt = 0; kt < 8; ++kt) {
            s8v a = *(const s8v*)(Pl + lx * SP + kt * 32 + quad * 8);
            av[0] = MFMA(a, vfrag[0][kt], av[0]);
            av[1] = MFMA(a, vfrag[1][kt], av[1]);
        }

        // ---- write P_lo, second PV pass ----
        __asm__ volatile("s_waitcnt lgkmcnt(0)" ::: "memory");
        #pragma unroll
        for (int mt = 0; mt < 16; ++mt) {
            unsigned short h0 = f2bs(acc[mt][0]);
            unsigned short h1 = f2bs(acc[mt][1]);
            unsigned short h2 = f2bs(acc[mt][2]);
            unsigned short h3 = f2bs(acc[mt][3]);
            uint2 w;
            w.x = (unsigned int)h0 | ((unsigned int)h1 << 16);
            w.y = (unsigned int)h2 | ((unsigned int)h3 << 16);
            *(uint2*)(Pl + lx * SP + mt * 16 + quad * 4) = w;
        }
        __asm__ volatile("s_waitcnt lgkmcnt(0)" ::: "memory");
        #pragma unroll
        for (int kt = 0; kt < 8; ++kt) {
            s8v a = *(const s8v*)(Pl + lx * SP + kt * 32 + quad * 8);
            av[0] = MFMA(a, vfrag[0][kt], av[0]);
            av[1] = MFMA(a, vfrag[1][kt], av[1]);
        }
        __asm__ volatile("s_waitcnt lgkmcnt(0)" ::: "memory");

        // ---- epilogue: normalize, store. C rows = query quad*4+r, cols = ch ntv*16+lx ----
        #pragma unroll
        for (int r = 0; r < 4; ++r) {
            const float lr = __shfl(l, quad * 4 + r, 64);
            const float inv = __builtin_amdgcn_rcpf(lr);
            const int qrow = q0 + quad * 4 + r;
            #pragma unroll
            for (int ntv = 0; ntv < 2; ++ntv) {
                obuf[((size_t)((b * 256 + qrow) * 16 + d)) * 128 + hd * 32 + ntv * 16 + lx]
                    = f2b(av[ntv][r] * inv);
            }
        }
    }
}

// ---------- Kernel 4: MFMA dimwise net. 32 points/block, fwd+tangent as M=64 ----------
__global__ __launch_bounds__(256) void dim_kernel(
    const float* t, const float* x,
    const float* p_b, const float* d_w0, const float* d_b0,
    const float* d_b1, const float* d_b2, const float* d_w3, const float* d_b3,
    const __hip_bfloat16* pwf, const __hip_bfloat16* w0f,
    const __hip_bfloat16* w1f, const __hip_bfloat16* w2f,
    const __hip_bfloat16* obuf, float* out)
{
    constexpr int SA = 264;
    constexpr int SO = 136;
    constexpr int SH = 72;
    __shared__ __hip_bfloat16 bufA[64 * SA];
    __shared__ __hip_bfloat16 bufB[64 * SA];
    __shared__ float xvs[32];

    const int tid  = threadIdx.x;
    const int wv   = tid >> 6, lane = tid & 63;
    const int lx   = lane & 15, quad = lane >> 4;
    const int p0   = blockIdx.x * 32;
    const float tval = t[0];

    auto ldA = [&](const __hip_bfloat16* buf, int stride, int m0, int k0) -> s8v {
        return *(const s8v*)(buf + (m0 + lx) * stride + k0 + quad * 8);
    };
    auto ldBf = [&](const __hip_bfloat16* wf, int NT, int kt, int nt) -> s8v {
        return *(const s8v*)(wf + (((size_t)(kt * NT + nt) * 64 + lane) << 3));
    };

    for (int idx = tid; idx < 512; idx += 256) {
        const int row = idx >> 4, ch = idx & 15;
        *(f4v*)(bufA + row * SO + ch * 8) = *(const f4v*)(obuf + (size_t)(p0 + row) * kH + ch * 8);
    }
    if (tid < 32) xvs[tid] = x[p0 + tid];
    __syncthreads();

    {
        f4v acc0 = {}, acc1 = {};
        #pragma unroll
        for (int ktile = 0; ktile < 4; ++ktile) {
            s8v b  = ldBf(pwf, 4, ktile, wv);
            s8v a0 = ldA(bufA, SO, 0,  ktile * 32);
            s8v a1 = ldA(bufA, SO, 16, ktile * 32);
            acc0 = MFMA(a0, b, acc0);
            acc1 = MFMA(a1, b, acc1);
        }
        const int n = wv * 16 + lx;
        const float bb = p_b[n];
        #pragma unroll
        for (int r = 0; r < 4; ++r) {
            bufB[(quad * 4 + r) * SH + n]        = f2b(acc0[r] + bb);
            bufB[(16 + quad * 4 + r) * SH + n]   = f2b(acc1[r] + bb);
        }
    }
    __syncthreads();

    {
        f4v acc[4][2] = {};
        #pragma unroll
        for (int ktile = 0; ktile < 2; ++ktile) {
            s8v a0 = ldA(bufB, SH, 0,  ktile * 32);
            s8v a1 = ldA(bufB, SH, 16, ktile * 32);
            #pragma unroll
            for (int j = 0; j < 4; ++j) {
                s8v b = ldBf(w0f, 16, ktile, wv * 4 + j);
                acc[j][0] = MFMA(a0, b, acc[j][0]);
                acc[j][1] = MFMA(a1, b, acc[j][1]);
            }
        }
        #pragma unroll
        for (int j = 0; j < 4; ++j) {
            const int n = (wv * 4 + j) * 16 + lx;
            const float base = d_b0[n] + tval * d_w0[n];
            const float wx   = d_w0[256 + n];
            #pragma unroll
            for (int mt = 0; mt < 2; ++mt)
            #pragma unroll
            for (int r = 0; r < 4; ++r) {
                const int m = mt * 16 + quad * 4 + r;
                const float z = tanh_fast(acc[j][mt][r] + base + xvs[m] * wx);
                bufA[m * SA + n]        = f2b(z);
                bufA[(m + 32) * SA + n] = f2b((1.f - z * z) * wx);
            }
        }
    }
    __syncthreads();

    {
        f4v acc[4][4] = {};
        #pragma unroll
        for (int ktile = 0; ktile < 8; ++ktile) {
            s8v a[4];
            #pragma unroll
            for (int mt = 0; mt < 4; ++mt) a[mt] = ldA(bufA, SA, mt * 16, ktile * 32);
            #pragma unroll
            for (int j = 0; j < 4; ++j) {
                s8v b = ldBf(w1f, 16, ktile, wv * 4 + j);
                #pragma unroll
                for (int mt = 0; mt < 4; ++mt) acc[j][mt] = MFMA(a[mt], b, acc[j][mt]);
            }
        }
        #pragma unroll
        for (int j = 0; j < 4; ++j) {
            const int n = (wv * 4 + j) * 16 + lx;
            const float b1 = d_b1[n];
            #pragma unroll
            for (int mt = 0; mt < 2; ++mt)
            #pragma unroll
            for (int r = 0; r < 4; ++r) {
                const int m = mt * 16 + quad * 4 + r;
                const float z  = tanh_fast(acc[j][mt][r] + b1);
                const float zd = (1.f - z * z) * acc[j][mt + 2][r];
                bufB[m * SA + n]        = f2b(z);
                bufB[(m + 32) * SA + n] = f2b(zd);
            }
        }
    }
    __syncthreads();

    {
        f4v acc[2][4] = {};
        #pragma unroll
        for (int ktile = 0; ktile < 8; ++ktile) {
            s8v a[4];
            #pragma unroll
            for (int mt = 0; mt < 4; ++mt) a[mt] = ldA(bufB, SA, mt * 16, ktile * 32);
            #pragma unroll
            for (int j = 0; j < 2; ++j) {
                s8v b = ldBf(w2f, 8, ktile, wv * 2 + j);
                #pragma unroll
                for (int mt = 0; mt < 4; ++mt) acc[j][mt] = MFMA(a[mt], b, acc[j][mt]);
            }
        }
        #pragma unroll
        for (int j = 0; j < 2; ++j) {
            const int n = (wv * 2 + j) * 16 + lx;
            const float b2 = d_b2[n];
            #pragma unroll
            for (int mt = 0; mt < 2; ++mt)
            #pragma unroll
            for (int r = 0; r < 4; ++r) {
                const int m = mt * 16 + quad * 4 + r;
                const float z  = tanh_fast(acc[j][mt][r] + b2);
                const float zd = (1.f - z * z) * acc[j][mt + 2][r];
                bufA[m * SO + n]        = f2b(z);
                bufA[(m + 32) * SO + n] = f2b(zd);
            }
        }
    }
    __syncthreads();

    {
        const int p = tid >> 3, s = tid & 7;
        float yv = 0.f, jv = 0.f;
        #pragma unroll
        for (int i = 0; i < 16; ++i) {
            const int n = s + i * 8;
            const float w = d_w3[n];
            yv += b2f(bufA[p * SO + n]) * w;
            jv += b2f(bufA[(p + 32) * SO + n]) * w;
        }
        #pragma unroll
        for (int off = 4; off > 0; off >>= 1) {
            yv += __shfl_down(yv, off, 8);
            jv += __shfl_down(jv, off, 8);
        }
        if (s == 0) {
            out[p0 + p]      = yv + d_b3[0];
            out[kP + p0 + p] = jv;
        }
    }
}

extern "C" void kernel_launch(void* const* d_in, const int* in_sizes, int n_in,
                              void* d_out, int out_size, void* d_ws, size_t ws_size,
                              hipStream_t stream)
{
    typedef const float* fp;
    fp t    = (fp)d_in[0];
    fp x    = (fp)d_in[1];
    fp q_w0 = (fp)d_in[2],  q_b0 = (fp)d_in[3];
    fp k_w0 = (fp)d_in[4],  k_b0 = (fp)d_in[5];
    fp v_w0 = (fp)d_in[6],  v_b0 = (fp)d_in[7];
    fp q_w1 = (fp)d_in[8],  q_b1 = (fp)d_in[9];
    fp k_w1 = (fp)d_in[10], k_b1 = (fp)d_in[11];
    fp v_w1 = (fp)d_in[12], v_b1 = (fp)d_in[13];
    fp q_w2 = (fp)d_in[14], q_b2 = (fp)d_in[15];
    fp k_w2 = (fp)d_in[16], k_b2 = (fp)d_in[17];
    fp v_w2 = (fp)d_in[18], v_b2 = (fp)d_in[19];
    fp p_w  = (fp)d_in[20], p_b  = (fp)d_in[21];
    fp d_w0 = (fp)d_in[22], d_b0 = (fp)d_in[23];
    fp d_w1 = (fp)d_in[24], d_b1 = (fp)d_in[25];
    fp d_w2 = (fp)d_in[26], d_b2 = (fp)d_in[27];
    fp d_w3 = (fp)d_in[28], d_b3 = (fp)d_in[29];

    __hip_bfloat16* wsb  = (__hip_bfloat16*)d_ws;
    __hip_bfloat16* kbuf = wsb;                                  // 2048*128
    __hip_bfloat16* vbuf = kbuf + (size_t)kBN * kH;              // 2048*128
    __hip_bfloat16* qbuf = vbuf + (size_t)kBN * kH;              // 2048*2048
    __hip_bfloat16* obuf = qbuf + (size_t)kBN * kD * kH;         // 32768*128
    __hip_bfloat16* pwf  = obuf + (size_t)kP * kH;               // 8192
    __hip_bfloat16* w0f  = pwf + 8192;                           // 16384
    __hip_bfloat16* w1f  = w0f + 16384;                          // 65536
    __hip_bfloat16* w2f  = w1f + 65536;                          // 32768
    float* qm0 = (float*)(w2f + 32768);                          // 4096
    float* qm1 = qm0 + 4096;                                     // 65536
    float* qm2 = qm1 + 65536;                                    // 524288

    float* out = (float*)d_out;

    prep_frag<<<60, 256, 0, stream>>>(p_w, d_w0, d_w1, d_w2, pwf, w0f, w1f, w2f);
    prep_qmask<<<2320, 256, 0, stream>>>(q_w0, q_w1, q_w2, qm0, qm1, qm2);
    kv_kernel<<<kBN / 4, 256, 0, stream>>>(x,
        k_w0, k_b0, k_w1, k_b1, k_w2, k_b2,
        v_w0, v_b0, v_w1, v_b1, v_w2, v_b2, kbuf, vbuf);
    q_kernel<<<kBN / 4, 256, 0, stream>>>(x, qm0, q_b0, qm1, q_b1, qm2, q_b2, qbuf);
    attn_kernel<<<kB * kD * 4 * 4, 64, 0, stream>>>(qbuf, kbuf, vbuf, obuf);
    dim_kernel<<<kP / 32, 256, 0, stream>>>(t, x, p_b, d_w0, d_b0, d_b1, d_b2, d_w3, d_b3,
        pwf, w0f, w1f, w2f, obuf, out);
}

// Round 5
// 218.359 us; speedup vs baseline: 3.7187x; 1.5719x over previous
//
#include <hip/hip_runtime.h>
#include <hip/hip_bf16.h>

constexpr int kB = 8, kN = 256, kD = 16, kHID = 256, kH = 128, kDH = 64, kdh = 32;
constexpr int kBN = kB * kN;          // 2048 rows
constexpr int kP  = kBN * kD;         // 32768 points

__device__ __forceinline__ float b2f(__hip_bfloat16 v) { return __bfloat162float(v); }
__device__ __forceinline__ __hip_bfloat16 f2b(float v) { return __float2bfloat16(v); }
__device__ __forceinline__ unsigned short f2bs(float v) {
    __hip_bfloat16 h = __float2bfloat16(v);
    return *(unsigned short*)&h;
}
__device__ __forceinline__ float bs2f(unsigned short s) {
    unsigned int u = ((unsigned int)s) << 16;
    return *(float*)&u;
}

__device__ __forceinline__ float tanh_fast(float v) {
    float e = __expf(2.f * v);
    return 1.f - 2.f * __builtin_amdgcn_rcpf(e + 1.f);
}

typedef short s8v  __attribute__((ext_vector_type(8)));   // 8 bf16 = 4 VGPRs
typedef float f4v  __attribute__((ext_vector_type(4)));
#define MFMA(a, b, c) __builtin_amdgcn_mfma_f32_16x16x32_bf16((a), (b), (c), 0, 0, 0)

// ---------- Prep: swizzle ALL weights into MFMA B-fragment layout (bf16) ----------
// frag[((kt*NT+nt)*64 + lane)*8 + j] = W[kt*32 + (lane>>4)*8 + j][nt*16 + (lane&15)]
// MADE masks folded into q fragments; layer-0 (K=16) zero-padded to K=32.
__global__ __launch_bounds__(256) void prep_frag(
    const float* p_w, const float* d_w0, const float* d_w1, const float* d_w2,
    const float* k_w0, const float* k_w1, const float* k_w2,
    const float* v_w0, const float* v_w1, const float* v_w2,
    const float* q_w0, const float* q_w1, const float* q_w2,
    __hip_bfloat16* pwf, __hip_bfloat16* w0f, __hip_bfloat16* w1f, __hip_bfloat16* w2f,
    __hip_bfloat16* k0f, __hip_bfloat16* k1f, __hip_bfloat16* k2f,
    __hip_bfloat16* v0f, __hip_bfloat16* v1f, __hip_bfloat16* v2f,
    __hip_bfloat16* q0f, __hip_bfloat16* q1f, __hip_bfloat16* q2f)
{
    const int tile = blockIdx.x * 4 + (threadIdx.x >> 6);
    const int lane = threadIdx.x & 63;
    const float* src; __hip_bfloat16* dst; int N, NT, local, Kreal = 1 << 30, mask = 0;
    if (tile < 16)        { src = p_w;        dst = pwf; N = 64;   NT = 4;   local = tile; }
    else if (tile < 48)   { src = d_w0 + 512; dst = w0f; N = 256;  NT = 16;  local = tile - 16; }
    else if (tile < 176)  { src = d_w1;       dst = w1f; N = 256;  NT = 16;  local = tile - 48; }
    else if (tile < 240)  { src = d_w2;       dst = w2f; N = 128;  NT = 8;   local = tile - 176; }
    else if (tile < 256)  { src = k_w0;       dst = k0f; N = 256;  NT = 16;  local = tile - 240; Kreal = 16; }
    else if (tile < 272)  { src = v_w0;       dst = v0f; N = 256;  NT = 16;  local = tile - 256; Kreal = 16; }
    else if (tile < 288)  { src = q_w0;       dst = q0f; N = 256;  NT = 16;  local = tile - 272; Kreal = 16; mask = 1; }
    else if (tile < 416)  { src = k_w1;       dst = k1f; N = 256;  NT = 16;  local = tile - 288; }
    else if (tile < 544)  { src = v_w1;       dst = v1f; N = 256;  NT = 16;  local = tile - 416; }
    else if (tile < 672)  { src = q_w1;       dst = q1f; N = 256;  NT = 16;  local = tile - 544; mask = 2; }
    else if (tile < 736)  { src = k_w2;       dst = k2f; N = 128;  NT = 8;   local = tile - 672; }
    else if (tile < 800)  { src = v_w2;       dst = v2f; N = 128;  NT = 8;   local = tile - 736; }
    else                  { src = q_w2;       dst = q2f; N = 2048; NT = 128; local = tile - 800; mask = 3; }
    const int kt = local / NT, nt = local % NT;
    const int row0 = kt * 32 + (lane >> 4) * 8;
    const int col  = nt * 16 + (lane & 15);
    __hip_bfloat16* o = dst + ((size_t)local * 64 + lane) * 8;
    #pragma unroll
    for (int j = 0; j < 8; ++j) {
        const int r = row0 + j;
        float w = (r < Kreal) ? src[(size_t)r * N + col] : 0.f;
        if (mask == 1 && !((col % 15) >= r))        w = 0.f;
        if (mask == 2 && !((col % 15) >= (r % 15))) w = 0.f;
        if (mask == 3 && !((col >> 7) > (r % 15)))  w = 0.f;
        o[j] = f2b(w);
    }
}

// ---------- Kernel 1: MFMA fused MLPs: k (3L tanh), v (3L tanh), q layers 0/1 (relu) ----------
// 32 rows/block, 64 blocks.
__global__ __launch_bounds__(256) void mlp_kernel(
    const float* x,
    const float* k_b0, const float* k_b1, const float* k_b2,
    const float* v_b0, const float* v_b1, const float* v_b2,
    const float* q_b0, const float* q_b1,
    const __hip_bfloat16* k0f, const __hip_bfloat16* k1f, const __hip_bfloat16* k2f,
    const __hip_bfloat16* v0f, const __hip_bfloat16* v1f, const __hip_bfloat16* v2f,
    const __hip_bfloat16* q0f, const __hip_bfloat16* q1f,
    __hip_bfloat16* kbuf, __hip_bfloat16* vbuf, __hip_bfloat16* h1q)
{
    constexpr int SA = 264;   // 256+8 pad, rows 16B-aligned
    constexpr int SX = 40;    // 32+8
    __shared__ __hip_bfloat16 xin[32 * SX];
    __shared__ __hip_bfloat16 bufA[32 * SA];
    __shared__ __hip_bfloat16 bufB[32 * SA];

    const int tid  = threadIdx.x;
    const int wv   = tid >> 6, lane = tid & 63;
    const int lx   = lane & 15, quad = lane >> 4;
    const int r0   = blockIdx.x * 32;

    auto ldA = [&](const __hip_bfloat16* buf, int stride, int m0, int k0) -> s8v {
        return *(const s8v*)(buf + (m0 + lx) * stride + k0 + quad * 8);
    };
    auto ldB = [&](const __hip_bfloat16* wf, int NT, int kt, int nt) -> s8v {
        return *(const s8v*)(wf + (((size_t)(kt * NT + nt) * 64 + lane) << 3));
    };

    // stage x rows (32 x 16 fp32) -> bf16 with zero pad to K=32
    for (int idx = tid; idx < 1024; idx += 256) {
        const int row = idx >> 5, c = idx & 31;
        xin[row * SX + c] = f2b(c < 16 ? x[(r0 + row) * kD + c] : 0.f);
    }

    const __hip_bfloat16* F0[3] = { k0f, v0f, q0f };
    const __hip_bfloat16* F1[3] = { k1f, v1f, q1f };
    const __hip_bfloat16* F2[2] = { k2f, v2f };
    const float* Ba0[3] = { k_b0, v_b0, q_b0 };
    const float* Ba1[3] = { k_b1, v_b1, q_b1 };
    const float* Ba2[2] = { k_b2, v_b2 };
    __hip_bfloat16* O2[2] = { kbuf, vbuf };

    for (int path = 0; path < 3; ++path) {
        __syncthreads();   // xin ready (p0); bufA/bufB safe to overwrite (p1/p2)

        // ---- L0: M=32, N=256, K=32 (padded) ----
        {
            f4v acc[4][2] = {};
            const s8v a0 = ldA(xin, SX, 0, 0);
            const s8v a1 = ldA(xin, SX, 16, 0);
            #pragma unroll
            for (int j = 0; j < 4; ++j) {
                s8v b = ldB(F0[path], 16, 0, wv * 4 + j);
                acc[j][0] = MFMA(a0, b, acc[j][0]);
                acc[j][1] = MFMA(a1, b, acc[j][1]);
            }
            #pragma unroll
            for (int j = 0; j < 4; ++j) {
                const int n = (wv * 4 + j) * 16 + lx;
                const float bb = Ba0[path][n];
                #pragma unroll
                for (int mt = 0; mt < 2; ++mt)
                #pragma unroll
                for (int r = 0; r < 4; ++r) {
                    const float v = acc[j][mt][r] + bb;
                    const float z = (path == 2) ? fmaxf(v, 0.f) : tanh_fast(v);
                    bufA[(mt * 16 + quad * 4 + r) * SA + n] = f2b(z);
                }
            }
        }
        __syncthreads();

        // ---- L1: M=32, N=256, K=256 ----
        {
            f4v acc[4][2] = {};
            #pragma unroll
            for (int kt = 0; kt < 8; ++kt) {
                const s8v a0 = ldA(bufA, SA, 0, kt * 32);
                const s8v a1 = ldA(bufA, SA, 16, kt * 32);
                #pragma unroll
                for (int j = 0; j < 4; ++j) {
                    s8v b = ldB(F1[path], 16, kt, wv * 4 + j);
                    acc[j][0] = MFMA(a0, b, acc[j][0]);
                    acc[j][1] = MFMA(a1, b, acc[j][1]);
                }
            }
            #pragma unroll
            for (int j = 0; j < 4; ++j) {
                const int n = (wv * 4 + j) * 16 + lx;
                const float bb = Ba1[path][n];
                #pragma unroll
                for (int mt = 0; mt < 2; ++mt)
                #pragma unroll
                for (int r = 0; r < 4; ++r) {
                    const int m = mt * 16 + quad * 4 + r;
                    const float v = acc[j][mt][r] + bb;
                    if (path == 2) {
                        h1q[(size_t)(r0 + m) * 256 + n] = f2b(fmaxf(v, 0.f));
                    } else {
                        bufB[m * SA + n] = f2b(tanh_fast(v));
                    }
                }
            }
        }
        if (path == 2) break;   // q stops at h1
        __syncthreads();

        // ---- L2: M=32, N=128, K=256, linear -> global ----
        {
            f4v acc[2][2] = {};
            #pragma unroll
            for (int kt = 0; kt < 8; ++kt) {
                const s8v a0 = ldA(bufB, SA, 0, kt * 32);
                const s8v a1 = ldA(bufB, SA, 16, kt * 32);
                #pragma unroll
                for (int j = 0; j < 2; ++j) {
                    s8v b = ldB(F2[path], 8, kt, wv * 2 + j);
                    acc[j][0] = MFMA(a0, b, acc[j][0]);
                    acc[j][1] = MFMA(a1, b, acc[j][1]);
                }
            }
            #pragma unroll
            for (int j = 0; j < 2; ++j) {
                const int n = (wv * 2 + j) * 16 + lx;
                const float bb = Ba2[path][n];
                #pragma unroll
                for (int mt = 0; mt < 2; ++mt)
                #pragma unroll
                for (int r = 0; r < 4; ++r) {
                    const int m = mt * 16 + quad * 4 + r;
                    O2[path][(size_t)(r0 + m) * kH + n] = f2b(acc[j][mt][r] + bb);
                }
            }
        }
    }
}

// ---------- Kernel 2: q layer-2 GEMM: M=2048, N=2048, K=256 with premasked fragments ----------
// grid = 64 row-tiles x 8 col-tiles
__global__ __launch_bounds__(256) void qgemm_kernel(
    const float* q_b2, const __hip_bfloat16* h1q, const __hip_bfloat16* q2f,
    __hip_bfloat16* qbuf)
{
    constexpr int SA = 264;
    __shared__ __hip_bfloat16 hin[32 * SA];

    const int tid  = threadIdx.x;
    const int wv   = tid >> 6, lane = tid & 63;
    const int lx   = lane & 15, quad = lane >> 4;
    const int ct   = blockIdx.x & 7;
    const int r0   = (blockIdx.x >> 3) * 32;

    for (int idx = tid; idx < 1024; idx += 256) {
        const int row = idx >> 5, seg = idx & 31;
        *(f4v*)(hin + row * SA + seg * 8) = *(const f4v*)(h1q + (size_t)(r0 + row) * 256 + seg * 8);
    }
    __syncthreads();

    f4v acc[4][2] = {};
    #pragma unroll
    for (int kt = 0; kt < 8; ++kt) {
        const s8v a0 = *(const s8v*)(hin + lx * SA + kt * 32 + quad * 8);
        const s8v a1 = *(const s8v*)(hin + (16 + lx) * SA + kt * 32 + quad * 8);
        #pragma unroll
        for (int j = 0; j < 4; ++j) {
            s8v b = *(const s8v*)(q2f + (((size_t)(kt * 128 + ct * 16 + wv * 4 + j) * 64 + lane) << 3));
            acc[j][0] = MFMA(a0, b, acc[j][0]);
            acc[j][1] = MFMA(a1, b, acc[j][1]);
        }
    }
    #pragma unroll
    for (int j = 0; j < 4; ++j) {
        const int col = ct * 256 + (wv * 4 + j) * 16 + lx;
        const float bb = q_b2[col];
        #pragma unroll
        for (int mt = 0; mt < 2; ++mt)
        #pragma unroll
        for (int r = 0; r < 4; ++r) {
            const int row = r0 + mt * 16 + quad * 4 + r;
            qbuf[(size_t)row * 2048 + col] = f2b(acc[j][mt][r] + bb);
        }
    }
}

// ---------- Kernel 3: MFMA attention. 1 wave/block, block=(b,d,hd,qw), 64 queries/wave ----------
__global__ __launch_bounds__(64, 2) void attn_kernel(
    const __hip_bfloat16* qbuf, const __hip_bfloat16* kbuf, const __hip_bfloat16* vbuf,
    __hip_bfloat16* obuf)
{
    constexpr int SP = 264;
    __shared__ short Pl[16 * SP];

    const int blk = blockIdx.x;                   // b*256 + d*16 + hd*4 + qw
    const int qw = blk & 3;
    const int hd = (blk >> 2) & 3;
    const int d  = (blk >> 4) & 15;
    const int b  = blk >> 8;

    const int lane = threadIdx.x;
    const int lx = lane & 15, quad = lane >> 4;

    const short* kb = (const short*)kbuf;
    const short* vb = (const short*)vbuf;
    const short* qb = (const short*)qbuf;

    s8v kfrag[16];
    #pragma unroll
    for (int mt = 0; mt < 16; ++mt)
        kfrag[mt] = *(const s8v*)(kb + (size_t)(b * 256 + mt * 16 + lx) * 128 + hd * 32 + quad * 8);

    s8v vfrag[2][8];
    #pragma unroll
    for (int ntv = 0; ntv < 2; ++ntv)
    #pragma unroll
    for (int kt = 0; kt < 8; ++kt) {
        s8v v;
        #pragma unroll
        for (int j = 0; j < 8; ++j)
            v[j] = vb[(size_t)(b * 256 + kt * 32 + quad * 8 + j) * 128 + hd * 32 + ntv * 16 + lx];
        vfrag[ntv][kt] = v;
    }

    const float scale = 0.17677669529663687f;     // 1/sqrt(32)

    for (int mi = 0; mi < 4; ++mi) {
        const int q0 = qw * 64 + mi * 16;

        s8v qfrag = *(const s8v*)(qb + (size_t)(b * 256 + q0 + lx) * 2048 + d * 128 + hd * 32 + quad * 8);

        f4v acc[16];
        #pragma unroll
        for (int mt = 0; mt < 16; ++mt) acc[mt] = f4v{0.f, 0.f, 0.f, 0.f};
        #pragma unroll
        for (int mt = 0; mt < 16; ++mt) acc[mt] = MFMA(kfrag[mt], qfrag, acc[mt]);

        const int qg = q0 + lx;
        float mx = -3.0e38f;
        #pragma unroll
        for (int mt = 0; mt < 16; ++mt)
        #pragma unroll
        for (int r = 0; r < 4; ++r) {
            const int key = mt * 16 + quad * 4 + r;
            float s = (key == qg) ? -3.0e38f : acc[mt][r];
            acc[mt][r] = s;
            mx = fmaxf(mx, s);
        }
        mx = fmaxf(mx, __shfl_xor(mx, 16, 64));
        mx = fmaxf(mx, __shfl_xor(mx, 32, 64));

        float l = 0.f;
        #pragma unroll
        for (int mt = 0; mt < 16; ++mt)
        #pragma unroll
        for (int r = 0; r < 4; ++r) {
            float p = __expf((acc[mt][r] - mx) * scale);
            acc[mt][r] = p;
            l += p;
        }
        l += __shfl_xor(l, 16, 64);
        l += __shfl_xor(l, 32, 64);

        #pragma unroll
        for (int mt = 0; mt < 16; ++mt) {
            unsigned short h0 = f2bs(acc[mt][0]);
            unsigned short h1 = f2bs(acc[mt][1]);
            unsigned short h2 = f2bs(acc[mt][2]);
            unsigned short h3 = f2bs(acc[mt][3]);
            uint2 w;
            w.x = (unsigned int)h0 | ((unsigned int)h1 << 16);
            w.y = (unsigned int)h2 | ((unsigned int)h3 << 16);
            *(uint2*)(Pl + lx * SP + mt * 16 + quad * 4) = w;
            acc[mt][0] -= bs2f(h0);
            acc[mt][1] -= bs2f(h1);
            acc[mt][2] -= bs2f(h2);
            acc[mt][3] -= bs2f(h3);
        }
        __asm__ volatile("s_waitcnt lgkmcnt(0)" ::: "memory");

        f4v av[2] = { f4v{0.f,0.f,0.f,0.f}, f4v{0.f,0.f,0.f,0.f} };
        #pragma unroll
        for (int kt = 0; kt < 8; ++kt) {
            s8v a = *(const s8v*)(Pl + lx * SP + kt * 32 + quad * 8);
            av[0] = MFMA(a, vfrag[0][kt], av[0]);
            av[1] = MFMA(a, vfrag[1][kt], av[1]);
        }

        __asm__ volatile("s_waitcnt lgkmcnt(0)" ::: "memory");
        #pragma unroll
        for (int mt = 0; mt < 16; ++mt) {
            unsigned short h0 = f2bs(acc[mt][0]);
            unsigned short h1 = f2bs(acc[mt][1]);
            unsigned short h2 = f2bs(acc[mt][2]);
            unsigned short h3 = f2bs(acc[mt][3]);
            uint2 w;
            w.x = (unsigned int)h0 | ((unsigned int)h1 << 16);
            w.y = (unsigned int)h2 | ((unsigned int)h3 << 16);
            *(uint2*)(Pl + lx * SP + mt * 16 + quad * 4) = w;
        }
        __asm__ volatile("s_waitcnt lgkmcnt(0)" ::: "memory");
        #pragma unroll
        for (int kt = 0; kt < 8; ++kt) {
            s8v a = *(const s8v*)(Pl + lx * SP + kt * 32 + quad * 8);
            av[0] = MFMA(a, vfrag[0][kt], av[0]);
            av[1] = MFMA(a, vfrag[1][kt], av[1]);
        }
        __asm__ volatile("s_waitcnt lgkmcnt(0)" ::: "memory");

        #pragma unroll
        for (int r = 0; r < 4; ++r) {
            const float lr = __shfl(l, quad * 4 + r, 64);
            const float inv = __builtin_amdgcn_rcpf(lr);
            const int qrow = q0 + quad * 4 + r;
            #pragma unroll
            for (int ntv = 0; ntv < 2; ++ntv) {
                obuf[((size_t)((b * 256 + qrow) * 16 + d)) * 128 + hd * 32 + ntv * 16 + lx]
                    = f2b(av[ntv][r] * inv);
            }
        }
    }
}

// ---------- Kernel 4: MFMA dimwise net. 32 points/block, fwd+tangent as M=64 ----------
__global__ __launch_bounds__(256) void dim_kernel(
    const float* t, const float* x,
    const float* p_b, const float* d_w0, const float* d_b0,
    const float* d_b1, const float* d_b2, const float* d_w3, const float* d_b3,
    const __hip_bfloat16* pwf, const __hip_bfloat16* w0f,
    const __hip_bfloat16* w1f, const __hip_bfloat16* w2f,
    const __hip_bfloat16* obuf, float* out)
{
    constexpr int SA = 264;
    constexpr int SO = 136;
    constexpr int SH = 72;
    __shared__ __hip_bfloat16 bufA[64 * SA];
    __shared__ __hip_bfloat16 bufB[64 * SA];
    __shared__ float xvs[32];

    const int tid  = threadIdx.x;
    const int wv   = tid >> 6, lane = tid & 63;
    const int lx   = lane & 15, quad = lane >> 4;
    const int p0   = blockIdx.x * 32;
    const float tval = t[0];

    auto ldA = [&](const __hip_bfloat16* buf, int stride, int m0, int k0) -> s8v {
        return *(const s8v*)(buf + (m0 + lx) * stride + k0 + quad * 8);
    };
    auto ldBf = [&](const __hip_bfloat16* wf, int NT, int kt, int nt) -> s8v {
        return *(const s8v*)(wf + (((size_t)(kt * NT + nt) * 64 + lane) << 3));
    };

    for (int idx = tid; idx < 512; idx += 256) {
        const int row = idx >> 4, ch = idx & 15;
        *(f4v*)(bufA + row * SO + ch * 8) = *(const f4v*)(obuf + (size_t)(p0 + row) * kH + ch * 8);
    }
    if (tid < 32) xvs[tid] = x[p0 + tid];
    __syncthreads();

    {
        f4v acc0 = {}, acc1 = {};
        #pragma unroll
        for (int ktile = 0; ktile < 4; ++ktile) {
            s8v b  = ldBf(pwf, 4, ktile, wv);
            s8v a0 = ldA(bufA, SO, 0,  ktile * 32);
            s8v a1 = ldA(bufA, SO, 16, ktile * 32);
            acc0 = MFMA(a0, b, acc0);
            acc1 = MFMA(a1, b, acc1);
        }
        const int n = wv * 16 + lx;
        const float bb = p_b[n];
        #pragma unroll
        for (int r = 0; r < 4; ++r) {
            bufB[(quad * 4 + r) * SH + n]        = f2b(acc0[r] + bb);
            bufB[(16 + quad * 4 + r) * SH + n]   = f2b(acc1[r] + bb);
        }
    }
    __syncthreads();

    {
        f4v acc[4][2] = {};
        #pragma unroll
        for (int ktile = 0; ktile < 2; ++ktile) {
            s8v a0 = ldA(bufB, SH, 0,  ktile * 32);
            s8v a1 = ldA(bufB, SH, 16, ktile * 32);
            #pragma unroll
            for (int j = 0; j < 4; ++j) {
                s8v b = ldBf(w0f, 16, ktile, wv * 4 + j);
                acc[j][0] = MFMA(a0, b, acc[j][0]);
                acc[j][1] = MFMA(a1, b, acc[j][1]);
            }
        }
        #pragma unroll
        for (int j = 0; j < 4; ++j) {
            const int n = (wv * 4 + j) * 16 + lx;
            const float base = d_b0[n] + tval * d_w0[n];
            const float wx   = d_w0[256 + n];
            #pragma unroll
            for (int mt = 0; mt < 2; ++mt)
            #pragma unroll
            for (int r = 0; r < 4; ++r) {
                const int m = mt * 16 + quad * 4 + r;
                const float z = tanh_fast(acc[j][mt][r] + base + xvs[m] * wx);
                bufA[m * SA + n]        = f2b(z);
                bufA[(m + 32) * SA + n] = f2b((1.f - z * z) * wx);
            }
        }
    }
    __syncthreads();

    {
        f4v acc[4][4] = {};
        #pragma unroll
        for (int ktile = 0; ktile < 8; ++ktile) {
            s8v a[4];
            #pragma unroll
            for (int mt = 0; mt < 4; ++mt) a[mt] = ldA(bufA, SA, mt * 16, ktile * 32);
            #pragma unroll
            for (int j = 0; j < 4; ++j) {
                s8v b = ldBf(w1f, 16, ktile, wv * 4 + j);
                #pragma unroll
                for (int mt = 0; mt < 4; ++mt) acc[j][mt] = MFMA(a[mt], b, acc[j][mt]);
            }
        }
        #pragma unroll
        for (int j = 0; j < 4; ++j) {
            const int n = (wv * 4 + j) * 16 + lx;
            const float b1 = d_b1[n];
            #pragma unroll
            for (int mt = 0; mt < 2; ++mt)
            #pragma unroll
            for (int r = 0; r < 4; ++r) {
                const int m = mt * 16 + quad * 4 + r;
                const float z  = tanh_fast(acc[j][mt][r] + b1);
                const float zd = (1.f - z * z) * acc[j][mt + 2][r];
                bufB[m * SA + n]        = f2b(z);
                bufB[(m + 32) * SA + n] = f2b(zd);
            }
        }
    }
    __syncthreads();

    {
        f4v acc[2][4] = {};
        #pragma unroll
        for (int ktile = 0; ktile < 8; ++ktile) {
            s8v a[4];
            #pragma unroll
            for (int mt = 0; mt < 4; ++mt) a[mt] = ldA(bufB, SA, mt * 16, ktile * 32);
            #pragma unroll
            for (int j = 0; j < 2; ++j) {
                s8v b = ldBf(w2f, 8, ktile, wv * 2 + j);
                #pragma unroll
                for (int mt = 0; mt < 4; ++mt) acc[j][mt] = MFMA(a[mt], b, acc[j][mt]);
            }
        }
        #pragma unroll
        for (int j = 0; j < 2; ++j) {
            const int n = (wv * 2 + j) * 16 + lx;
            const float b2 = d_b2[n];
            #pragma unroll
            for (int mt = 0; mt < 2; ++mt)
            #pragma unroll
            for (int r = 0; r < 4; ++r) {
                const int m = mt * 16 + quad * 4 + r;
                const float z  = tanh_fast(acc[j][mt][r] + b2);
                const float zd = (1.f - z * z) * acc[j][mt + 2][r];
                bufA[m * SO + n]        = f2b(z);
                bufA[(m + 32) * SO + n] = f2b(zd);
            }
        }
    }
    __syncthreads();

    {
        const int p = tid >> 3, s = tid & 7;
        float yv = 0.f, jv = 0.f;
        #pragma unroll
        for (int i = 0; i < 16; ++i) {
            const int n = s + i * 8;
            const float w = d_w3[n];
            yv += b2f(bufA[p * SO + n]) * w;
            jv += b2f(bufA[(p + 32) * SO + n]) * w;
        }
        #pragma unroll
        for (int off = 4; off > 0; off >>= 1) {
            yv += __shfl_down(yv, off, 8);
            jv += __shfl_down(jv, off, 8);
        }
        if (s == 0) {
            out[p0 + p]      = yv + d_b3[0];
            out[kP + p0 + p] = jv;
        }
    }
}

extern "C" void kernel_launch(void* const* d_in, const int* in_sizes, int n_in,
                              void* d_out, int out_size, void* d_ws, size_t ws_size,
                              hipStream_t stream)
{
    typedef const float* fp;
    fp t    = (fp)d_in[0];
    fp x    = (fp)d_in[1];
    fp q_w0 = (fp)d_in[2],  q_b0 = (fp)d_in[3];
    fp k_w0 = (fp)d_in[4],  k_b0 = (fp)d_in[5];
    fp v_w0 = (fp)d_in[6],  v_b0 = (fp)d_in[7];
    fp q_w1 = (fp)d_in[8],  q_b1 = (fp)d_in[9];
    fp k_w1 = (fp)d_in[10], k_b1 = (fp)d_in[11];
    fp v_w1 = (fp)d_in[12], v_b1 = (fp)d_in[13];
    fp q_w2 = (fp)d_in[14], q_b2 = (fp)d_in[15];
    fp k_w2 = (fp)d_in[16], k_b2 = (fp)d_in[17];
    fp v_w2 = (fp)d_in[18], v_b2 = (fp)d_in[19];
    fp p_w  = (fp)d_in[20], p_b  = (fp)d_in[21];
    fp d_w0 = (fp)d_in[22], d_b0 = (fp)d_in[23];
    fp d_w1 = (fp)d_in[24], d_b1 = (fp)d_in[25];
    fp d_w2 = (fp)d_in[26], d_b2 = (fp)d_in[27];
    fp d_w3 = (fp)d_in[28], d_b3 = (fp)d_in[29];

    __hip_bfloat16* wsb  = (__hip_bfloat16*)d_ws;
    __hip_bfloat16* kbuf = wsb;                                  // 2048*128
    __hip_bfloat16* vbuf = kbuf + (size_t)kBN * kH;              // 2048*128
    __hip_bfloat16* qbuf = vbuf + (size_t)kBN * kH;              // 2048*2048
    __hip_bfloat16* obuf = qbuf + (size_t)kBN * kD * kH;         // 32768*128
    __hip_bfloat16* pwf  = obuf + (size_t)kP * kH;               // 8192
    __hip_bfloat16* w0f  = pwf + 8192;                           // 16384
    __hip_bfloat16* w1f  = w0f + 16384;                          // 65536
    __hip_bfloat16* w2f  = w1f + 65536;                          // 32768
    __hip_bfloat16* k0f  = w2f + 32768;                          // 8192
    __hip_bfloat16* v0f  = k0f + 8192;                           // 8192
    __hip_bfloat16* q0f  = v0f + 8192;                           // 8192
    __hip_bfloat16* k1f  = q0f + 8192;                           // 65536
    __hip_bfloat16* v1f  = k1f + 65536;                          // 65536
    __hip_bfloat16* q1f  = v1f + 65536;                          // 65536
    __hip_bfloat16* k2f  = q1f + 65536;                          // 32768
    __hip_bfloat16* v2f  = k2f + 32768;                          // 32768
    __hip_bfloat16* q2f  = v2f + 32768;                          // 524288
    __hip_bfloat16* h1q  = q2f + 524288;                         // 2048*256

    float* out = (float*)d_out;

    prep_frag<<<456, 256, 0, stream>>>(p_w, d_w0, d_w1, d_w2,
        k_w0, k_w1, k_w2, v_w0, v_w1, v_w2, q_w0, q_w1, q_w2,
        pwf, w0f, w1f, w2f, k0f, k1f, k2f, v0f, v1f, v2f, q0f, q1f, q2f);
    mlp_kernel<<<kBN / 32, 256, 0, stream>>>(x,
        k_b0, k_b1, k_b2, v_b0, v_b1, v_b2, q_b0, q_b1,
        k0f, k1f, k2f, v0f, v1f, v2f, q0f, q1f, kbuf, vbuf, h1q);
    qgemm_kernel<<<(kBN / 32) * 8, 256, 0, stream>>>(q_b2, h1q, q2f, qbuf);
    attn_kernel<<<kB * kD * 4 * 4, 64, 0, stream>>>(qbuf, kbuf, vbuf, obuf);
    dim_kernel<<<kP / 32, 256, 0, stream>>>(t, x, p_b, d_w0, d_b0, d_b1, d_b2, d_w3, d_b3,
        pwf, w0f, w1f, w2f, obuf, out);
}

// Round 6
// 215.058 us; speedup vs baseline: 3.7758x; 1.0153x over previous
//
#include <hip/hip_runtime.h>
#include <hip/hip_bf16.h>

constexpr int kB = 8, kN = 256, kD = 16, kHID = 256, kH = 128, kDH = 64, kdh = 32;
constexpr int kBN = kB * kN;          // 2048 rows
constexpr int kP  = kBN * kD;         // 32768 points

__device__ __forceinline__ float b2f(__hip_bfloat16 v) { return __bfloat162float(v); }
__device__ __forceinline__ __hip_bfloat16 f2b(float v) { return __float2bfloat16(v); }
__device__ __forceinline__ unsigned short f2bs(float v) {
    __hip_bfloat16 h = __float2bfloat16(v);
    return *(unsigned short*)&h;
}

__device__ __forceinline__ float tanh_fast(float v) {
    float e = __expf(2.f * v);
    return 1.f - 2.f * __builtin_amdgcn_rcpf(e + 1.f);
}

typedef short s8v  __attribute__((ext_vector_type(8)));   // 8 bf16 = 4 VGPRs
typedef float f4v  __attribute__((ext_vector_type(4)));
#define MFMA(a, b, c) __builtin_amdgcn_mfma_f32_16x16x32_bf16((a), (b), (c), 0, 0, 0)

// ---------- Prep: swizzle ALL weights into MFMA B-fragment layout (bf16) ----------
__global__ __launch_bounds__(256) void prep_frag(
    const float* p_w, const float* d_w0, const float* d_w1, const float* d_w2,
    const float* k_w0, const float* k_w1, const float* k_w2,
    const float* v_w0, const float* v_w1, const float* v_w2,
    const float* q_w0, const float* q_w1, const float* q_w2,
    __hip_bfloat16* pwf, __hip_bfloat16* w0f, __hip_bfloat16* w1f, __hip_bfloat16* w2f,
    __hip_bfloat16* k0f, __hip_bfloat16* k1f, __hip_bfloat16* k2f,
    __hip_bfloat16* v0f, __hip_bfloat16* v1f, __hip_bfloat16* v2f,
    __hip_bfloat16* q0f, __hip_bfloat16* q1f, __hip_bfloat16* q2f)
{
    const int tile = blockIdx.x * 4 + (threadIdx.x >> 6);
    const int lane = threadIdx.x & 63;
    const float* src; __hip_bfloat16* dst; int N, NT, local, Kreal = 1 << 30, mask = 0;
    if (tile < 16)        { src = p_w;        dst = pwf; N = 64;   NT = 4;   local = tile; }
    else if (tile < 48)   { src = d_w0 + 512; dst = w0f; N = 256;  NT = 16;  local = tile - 16; }
    else if (tile < 176)  { src = d_w1;       dst = w1f; N = 256;  NT = 16;  local = tile - 48; }
    else if (tile < 240)  { src = d_w2;       dst = w2f; N = 128;  NT = 8;   local = tile - 176; }
    else if (tile < 256)  { src = k_w0;       dst = k0f; N = 256;  NT = 16;  local = tile - 240; Kreal = 16; }
    else if (tile < 272)  { src = v_w0;       dst = v0f; N = 256;  NT = 16;  local = tile - 256; Kreal = 16; }
    else if (tile < 288)  { src = q_w0;       dst = q0f; N = 256;  NT = 16;  local = tile - 272; Kreal = 16; mask = 1; }
    else if (tile < 416)  { src = k_w1;       dst = k1f; N = 256;  NT = 16;  local = tile - 288; }
    else if (tile < 544)  { src = v_w1;       dst = v1f; N = 256;  NT = 16;  local = tile - 416; }
    else if (tile < 672)  { src = q_w1;       dst = q1f; N = 256;  NT = 16;  local = tile - 544; mask = 2; }
    else if (tile < 736)  { src = k_w2;       dst = k2f; N = 128;  NT = 8;   local = tile - 672; }
    else if (tile < 800)  { src = v_w2;       dst = v2f; N = 128;  NT = 8;   local = tile - 736; }
    else                  { src = q_w2;       dst = q2f; N = 2048; NT = 128; local = tile - 800; mask = 3; }
    const int kt = local / NT, nt = local % NT;
    const int row0 = kt * 32 + (lane >> 4) * 8;
    const int col  = nt * 16 + (lane & 15);
    __hip_bfloat16* o = dst + ((size_t)local * 64 + lane) * 8;
    #pragma unroll
    for (int j = 0; j < 8; ++j) {
        const int r = row0 + j;
        float w = (r < Kreal) ? src[(size_t)r * N + col] : 0.f;
        if (mask == 1 && !((col % 15) >= r))        w = 0.f;
        if (mask == 2 && !((col % 15) >= (r % 15))) w = 0.f;
        if (mask == 3 && !((col >> 7) > (r % 15)))  w = 0.f;
        o[j] = f2b(w);
    }
}

// ---------- Kernel 1: MFMA fused MLPs: k (3L tanh), v (3L tanh), q layers 0/1 (relu) ----------
__global__ __launch_bounds__(256) void mlp_kernel(
    const float* x,
    const float* k_b0, const float* k_b1, const float* k_b2,
    const float* v_b0, const float* v_b1, const float* v_b2,
    const float* q_b0, const float* q_b1,
    const __hip_bfloat16* k0f, const __hip_bfloat16* k1f, const __hip_bfloat16* k2f,
    const __hip_bfloat16* v0f, const __hip_bfloat16* v1f, const __hip_bfloat16* v2f,
    const __hip_bfloat16* q0f, const __hip_bfloat16* q1f,
    __hip_bfloat16* kbuf, __hip_bfloat16* vbuf, __hip_bfloat16* h1q)
{
    constexpr int SA = 264;
    constexpr int SX = 40;
    __shared__ __hip_bfloat16 xin[32 * SX];
    __shared__ __hip_bfloat16 bufA[32 * SA];
    __shared__ __hip_bfloat16 bufB[32 * SA];

    const int tid  = threadIdx.x;
    const int wv   = tid >> 6, lane = tid & 63;
    const int lx   = lane & 15, quad = lane >> 4;
    const int r0   = blockIdx.x * 32;

    auto ldA = [&](const __hip_bfloat16* buf, int stride, int m0, int k0) -> s8v {
        return *(const s8v*)(buf + (m0 + lx) * stride + k0 + quad * 8);
    };
    auto ldB = [&](const __hip_bfloat16* wf, int NT, int kt, int nt) -> s8v {
        return *(const s8v*)(wf + (((size_t)(kt * NT + nt) * 64 + lane) << 3));
    };

    for (int idx = tid; idx < 1024; idx += 256) {
        const int row = idx >> 5, c = idx & 31;
        xin[row * SX + c] = f2b(c < 16 ? x[(r0 + row) * kD + c] : 0.f);
    }

    const __hip_bfloat16* F0[3] = { k0f, v0f, q0f };
    const __hip_bfloat16* F1[3] = { k1f, v1f, q1f };
    const __hip_bfloat16* F2[2] = { k2f, v2f };
    const float* Ba0[3] = { k_b0, v_b0, q_b0 };
    const float* Ba1[3] = { k_b1, v_b1, q_b1 };
    const float* Ba2[2] = { k_b2, v_b2 };
    __hip_bfloat16* O2[2] = { kbuf, vbuf };

    for (int path = 0; path < 3; ++path) {
        __syncthreads();

        {   // L0: M=32, N=256, K=32 (padded)
            f4v acc[4][2] = {};
            const s8v a0 = ldA(xin, SX, 0, 0);
            const s8v a1 = ldA(xin, SX, 16, 0);
            #pragma unroll
            for (int j = 0; j < 4; ++j) {
                s8v b = ldB(F0[path], 16, 0, wv * 4 + j);
                acc[j][0] = MFMA(a0, b, acc[j][0]);
                acc[j][1] = MFMA(a1, b, acc[j][1]);
            }
            #pragma unroll
            for (int j = 0; j < 4; ++j) {
                const int n = (wv * 4 + j) * 16 + lx;
                const float bb = Ba0[path][n];
                #pragma unroll
                for (int mt = 0; mt < 2; ++mt)
                #pragma unroll
                for (int r = 0; r < 4; ++r) {
                    const float v = acc[j][mt][r] + bb;
                    const float z = (path == 2) ? fmaxf(v, 0.f) : tanh_fast(v);
                    bufA[(mt * 16 + quad * 4 + r) * SA + n] = f2b(z);
                }
            }
        }
        __syncthreads();

        {   // L1: M=32, N=256, K=256
            f4v acc[4][2] = {};
            #pragma unroll
            for (int kt = 0; kt < 8; ++kt) {
                const s8v a0 = ldA(bufA, SA, 0, kt * 32);
                const s8v a1 = ldA(bufA, SA, 16, kt * 32);
                #pragma unroll
                for (int j = 0; j < 4; ++j) {
                    s8v b = ldB(F1[path], 16, kt, wv * 4 + j);
                    acc[j][0] = MFMA(a0, b, acc[j][0]);
                    acc[j][1] = MFMA(a1, b, acc[j][1]);
                }
            }
            #pragma unroll
            for (int j = 0; j < 4; ++j) {
                const int n = (wv * 4 + j) * 16 + lx;
                const float bb = Ba1[path][n];
                #pragma unroll
                for (int mt = 0; mt < 2; ++mt)
                #pragma unroll
                for (int r = 0; r < 4; ++r) {
                    const int m = mt * 16 + quad * 4 + r;
                    const float v = acc[j][mt][r] + bb;
                    if (path == 2) {
                        h1q[(size_t)(r0 + m) * 256 + n] = f2b(fmaxf(v, 0.f));
                    } else {
                        bufB[m * SA + n] = f2b(tanh_fast(v));
                    }
                }
            }
        }
        if (path == 2) break;
        __syncthreads();

        {   // L2: M=32, N=128, K=256, linear -> global
            f4v acc[2][2] = {};
            #pragma unroll
            for (int kt = 0; kt < 8; ++kt) {
                const s8v a0 = ldA(bufB, SA, 0, kt * 32);
                const s8v a1 = ldA(bufB, SA, 16, kt * 32);
                #pragma unroll
                for (int j = 0; j < 2; ++j) {
                    s8v b = ldB(F2[path], 8, kt, wv * 2 + j);
                    acc[j][0] = MFMA(a0, b, acc[j][0]);
                    acc[j][1] = MFMA(a1, b, acc[j][1]);
                }
            }
            #pragma unroll
            for (int j = 0; j < 2; ++j) {
                const int n = (wv * 2 + j) * 16 + lx;
                const float bb = Ba2[path][n];
                #pragma unroll
                for (int mt = 0; mt < 2; ++mt)
                #pragma unroll
                for (int r = 0; r < 4; ++r) {
                    const int m = mt * 16 + quad * 4 + r;
                    O2[path][(size_t)(r0 + m) * kH + n] = f2b(acc[j][mt][r] + bb);
                }
            }
        }
    }
}

// ---------- Kernel 2: q layer-2 GEMM. Scale 1/sqrt(32) folded into output. ----------
__global__ __launch_bounds__(256) void qgemm_kernel(
    const float* q_b2, const __hip_bfloat16* h1q, const __hip_bfloat16* q2f,
    __hip_bfloat16* qbuf)
{
    constexpr int SA = 264;
    __shared__ __hip_bfloat16 hin[32 * SA];

    const int tid  = threadIdx.x;
    const int wv   = tid >> 6, lane = tid & 63;
    const int lx   = lane & 15, quad = lane >> 4;
    const int ct   = blockIdx.x & 7;
    const int r0   = (blockIdx.x >> 3) * 32;

    for (int idx = tid; idx < 1024; idx += 256) {
        const int row = idx >> 5, seg = idx & 31;
        *(f4v*)(hin + row * SA + seg * 8) = *(const f4v*)(h1q + (size_t)(r0 + row) * 256 + seg * 8);
    }
    __syncthreads();

    f4v acc[4][2] = {};
    #pragma unroll
    for (int kt = 0; kt < 8; ++kt) {
        const s8v a0 = *(const s8v*)(hin + lx * SA + kt * 32 + quad * 8);
        const s8v a1 = *(const s8v*)(hin + (16 + lx) * SA + kt * 32 + quad * 8);
        #pragma unroll
        for (int j = 0; j < 4; ++j) {
            s8v b = *(const s8v*)(q2f + (((size_t)(kt * 128 + ct * 16 + wv * 4 + j) * 64 + lane) << 3));
            acc[j][0] = MFMA(a0, b, acc[j][0]);
            acc[j][1] = MFMA(a1, b, acc[j][1]);
        }
    }
    const float scale = 0.17677669529663687f;     // 1/sqrt(32)
    #pragma unroll
    for (int j = 0; j < 4; ++j) {
        const int col = ct * 256 + (wv * 4 + j) * 16 + lx;
        const float bb = q_b2[col];
        #pragma unroll
        for (int mt = 0; mt < 2; ++mt)
        #pragma unroll
        for (int r = 0; r < 4; ++r) {
            const int row = r0 + mt * 16 + quad * 4 + r;
            qbuf[(size_t)row * 2048 + col] = f2b((acc[j][mt][r] + bb) * scale);
        }
    }
}

// ---------- Kernel 3: MFMA attention. 4 waves/block (wave = 64-query group), fp32 obuf ----------
__global__ __launch_bounds__(256, 2) void attn_kernel(
    const __hip_bfloat16* qbuf, const __hip_bfloat16* kbuf, const __hip_bfloat16* vbuf,
    float* obuf)
{
    constexpr int SP = 264;
    __shared__ short Pl[4][16 * SP];

    const int blk = blockIdx.x;                   // b*64 + d*4 + hd
    const int hd = blk & 3;
    const int d  = (blk >> 2) & 15;
    const int b  = blk >> 6;

    const int wv   = threadIdx.x >> 6;            // query group (was qw)
    const int lane = threadIdx.x & 63;
    const int lx = lane & 15, quad = lane >> 4;
    short* Pw = &Pl[wv][0];

    const short* kb = (const short*)kbuf;
    const short* vb = (const short*)vbuf;
    const short* qb = (const short*)qbuf;

    s8v kfrag[16];
    #pragma unroll
    for (int mt = 0; mt < 16; ++mt)
        kfrag[mt] = *(const s8v*)(kb + (size_t)(b * 256 + mt * 16 + lx) * 128 + hd * 32 + quad * 8);

    s8v vfrag[2][8];
    #pragma unroll
    for (int ntv = 0; ntv < 2; ++ntv)
    #pragma unroll
    for (int kt = 0; kt < 8; ++kt) {
        s8v v;
        #pragma unroll
        for (int j = 0; j < 8; ++j)
            v[j] = vb[(size_t)(b * 256 + kt * 32 + quad * 8 + j) * 128 + hd * 32 + ntv * 16 + lx];
        vfrag[ntv][kt] = v;
    }

    const float LOG2E = 1.4426950408889634f;

    for (int mi = 0; mi < 4; ++mi) {
        const int q0 = wv * 64 + mi * 16;

        s8v qfrag = *(const s8v*)(qb + (size_t)(b * 256 + q0 + lx) * 2048 + d * 128 + hd * 32 + quad * 8);

        f4v acc[16];
        #pragma unroll
        for (int mt = 0; mt < 16; ++mt) acc[mt] = f4v{0.f, 0.f, 0.f, 0.f};
        #pragma unroll
        for (int mt = 0; mt < 16; ++mt) acc[mt] = MFMA(kfrag[mt], qfrag, acc[mt]);

        // scores already scaled (folded into qbuf). Mask diagonal, row max over keys.
        const int qg = q0 + lx;
        float mx = -3.0e38f;
        #pragma unroll
        for (int mt = 0; mt < 16; ++mt)
        #pragma unroll
        for (int r = 0; r < 4; ++r) {
            const int key = mt * 16 + quad * 4 + r;
            float s = (key == qg) ? -3.0e38f : acc[mt][r];
            acc[mt][r] = s;
            mx = fmaxf(mx, s);
        }
        mx = fmaxf(mx, __shfl_xor(mx, 16, 64));
        mx = fmaxf(mx, __shfl_xor(mx, 32, 64));

        const float nmxc = -mx * LOG2E;
        float l = 0.f;
        #pragma unroll
        for (int mt = 0; mt < 16; ++mt)
        #pragma unroll
        for (int r = 0; r < 4; ++r) {
            float p = exp2f(__builtin_fmaf(acc[mt][r], LOG2E, nmxc));
            acc[mt][r] = p;
            l += p;
        }
        l += __shfl_xor(l, 16, 64);
        l += __shfl_xor(l, 32, 64);

        // P (bf16) -> wave-private LDS in A-layout: Pw[query=lx][key]
        #pragma unroll
        for (int mt = 0; mt < 16; ++mt) {
            unsigned short h0 = f2bs(acc[mt][0]);
            unsigned short h1 = f2bs(acc[mt][1]);
            unsigned short h2 = f2bs(acc[mt][2]);
            unsigned short h3 = f2bs(acc[mt][3]);
            uint2 w;
            w.x = (unsigned int)h0 | ((unsigned int)h1 << 16);
            w.y = (unsigned int)h2 | ((unsigned int)h3 << 16);
            *(uint2*)(Pw + lx * SP + mt * 16 + quad * 4) = w;
        }
        __asm__ volatile("s_waitcnt lgkmcnt(0)" ::: "memory");

        f4v av[2] = { f4v{0.f,0.f,0.f,0.f}, f4v{0.f,0.f,0.f,0.f} };
        #pragma unroll
        for (int kt = 0; kt < 8; ++kt) {
            s8v a = *(const s8v*)(Pw + lx * SP + kt * 32 + quad * 8);
            av[0] = MFMA(a, vfrag[0][kt], av[0]);
            av[1] = MFMA(a, vfrag[1][kt], av[1]);
        }
        __asm__ volatile("s_waitcnt lgkmcnt(0)" ::: "memory");

        #pragma unroll
        for (int r = 0; r < 4; ++r) {
            const float lr = __shfl(l, quad * 4 + r, 64);
            const float inv = __builtin_amdgcn_rcpf(lr);
            const int qrow = q0 + quad * 4 + r;
            #pragma unroll
            for (int ntv = 0; ntv < 2; ++ntv) {
                obuf[((size_t)((b * 256 + qrow) * 16 + d)) * 128 + hd * 32 + ntv * 16 + lx]
                    = av[ntv][r] * inv;
            }
        }
    }
}

// ---------- Kernel 4: MFMA dimwise net. 32 points/block, fwd+tangent as M=64 ----------
__global__ __launch_bounds__(256) void dim_kernel(
    const float* t, const float* x,
    const float* p_b, const float* d_w0, const float* d_b0,
    const float* d_b1, const float* d_b2, const float* d_w3, const float* d_b3,
    const __hip_bfloat16* pwf, const __hip_bfloat16* w0f,
    const __hip_bfloat16* w1f, const __hip_bfloat16* w2f,
    const float* obuf, float* out)
{
    constexpr int SA = 264;
    constexpr int SO = 136;
    constexpr int SH = 72;
    __shared__ __hip_bfloat16 bufA[64 * SA];
    __shared__ __hip_bfloat16 bufB[64 * SA];
    __shared__ float xvs[32];

    const int tid  = threadIdx.x;
    const int wv   = tid >> 6, lane = tid & 63;
    const int lx   = lane & 15, quad = lane >> 4;
    const int p0   = blockIdx.x * 32;
    const float tval = t[0];

    auto ldA = [&](const __hip_bfloat16* buf, int stride, int m0, int k0) -> s8v {
        return *(const s8v*)(buf + (m0 + lx) * stride + k0 + quad * 8);
    };
    auto ldBf = [&](const __hip_bfloat16* wf, int NT, int kt, int nt) -> s8v {
        return *(const s8v*)(wf + (((size_t)(kt * NT + nt) * 64 + lane) << 3));
    };

    // stage obuf (fp32) -> bf16 LDS rows
    for (int idx = tid; idx < 1024; idx += 256) {
        const int row = idx >> 5, seg = idx & 31;
        f4v v = *(const f4v*)(obuf + (size_t)(p0 + row) * kH + seg * 4);
        __hip_bfloat16* dst = bufA + row * SO + seg * 4;
        dst[0] = f2b(v[0]); dst[1] = f2b(v[1]); dst[2] = f2b(v[2]); dst[3] = f2b(v[3]);
    }
    if (tid < 32) xvs[tid] = x[p0 + tid];
    __syncthreads();

    {
        f4v acc0 = {}, acc1 = {};
        #pragma unroll
        for (int ktile = 0; ktile < 4; ++ktile) {
            s8v b  = ldBf(pwf, 4, ktile, wv);
            s8v a0 = ldA(bufA, SO, 0,  ktile * 32);
            s8v a1 = ldA(bufA, SO, 16, ktile * 32);
            acc0 = MFMA(a0, b, acc0);
            acc1 = MFMA(a1, b, acc1);
        }
        const int n = wv * 16 + lx;
        const float bb = p_b[n];
        #pragma unroll
        for (int r = 0; r < 4; ++r) {
            bufB[(quad * 4 + r) * SH + n]        = f2b(acc0[r] + bb);
            bufB[(16 + quad * 4 + r) * SH + n]   = f2b(acc1[r] + bb);
        }
    }
    __syncthreads();

    {
        f4v acc[4][2] = {};
        #pragma unroll
        for (int ktile = 0; ktile < 2; ++ktile) {
            s8v a0 = ldA(bufB, SH, 0,  ktile * 32);
            s8v a1 = ldA(bufB, SH, 16, ktile * 32);
            #pragma unroll
            for (int j = 0; j < 4; ++j) {
                s8v b = ldBf(w0f, 16, ktile, wv * 4 + j);
                acc[j][0] = MFMA(a0, b, acc[j][0]);
                acc[j][1] = MFMA(a1, b, acc[j][1]);
            }
        }
        #pragma unroll
        for (int j = 0; j < 4; ++j) {
            const int n = (wv * 4 + j) * 16 + lx;
            const float base = d_b0[n] + tval * d_w0[n];
            const float wx   = d_w0[256 + n];
            #pragma unroll
            for (int mt = 0; mt < 2; ++mt)
            #pragma unroll
            for (int r = 0; r < 4; ++r) {
                const int m = mt * 16 + quad * 4 + r;
                const float z = tanh_fast(acc[j][mt][r] + base + xvs[m] * wx);
                bufA[m * SA + n]        = f2b(z);
                bufA[(m + 32) * SA + n] = f2b((1.f - z * z) * wx);
            }
        }
    }
    __syncthreads();

    {
        f4v acc[4][4] = {};
        #pragma unroll
        for (int ktile = 0; ktile < 8; ++ktile) {
            s8v a[4];
            #pragma unroll
            for (int mt = 0; mt < 4; ++mt) a[mt] = ldA(bufA, SA, mt * 16, ktile * 32);
            #pragma unroll
            for (int j = 0; j < 4; ++j) {
                s8v b = ldBf(w1f, 16, ktile, wv * 4 + j);
                #pragma unroll
                for (int mt = 0; mt < 4; ++mt) acc[j][mt] = MFMA(a[mt], b, acc[j][mt]);
            }
        }
        #pragma unroll
        for (int j = 0; j < 4; ++j) {
            const int n = (wv * 4 + j) * 16 + lx;
            const float b1 = d_b1[n];
            #pragma unroll
            for (int mt = 0; mt < 2; ++mt)
            #pragma unroll
            for (int r = 0; r < 4; ++r) {
                const int m = mt * 16 + quad * 4 + r;
                const float z  = tanh_fast(acc[j][mt][r] + b1);
                const float zd = (1.f - z * z) * acc[j][mt + 2][r];
                bufB[m * SA + n]        = f2b(z);
                bufB[(m + 32) * SA + n] = f2b(zd);
            }
        }
    }
    __syncthreads();

    {
        f4v acc[2][4] = {};
        #pragma unroll
        for (int ktile = 0; ktile < 8; ++ktile) {
            s8v a[4];
            #pragma unroll
            for (int mt = 0; mt < 4; ++mt) a[mt] = ldA(bufB, SA, mt * 16, ktile * 32);
            #pragma unroll
            for (int j = 0; j < 2; ++j) {
                s8v b = ldBf(w2f, 8, ktile, wv * 2 + j);
                #pragma unroll
                for (int mt = 0; mt < 4; ++mt) acc[j][mt] = MFMA(a[mt], b, acc[j][mt]);
            }
        }
        #pragma unroll
        for (int j = 0; j < 2; ++j) {
            const int n = (wv * 2 + j) * 16 + lx;
            const float b2 = d_b2[n];
            #pragma unroll
            for (int mt = 0; mt < 2; ++mt)
            #pragma unroll
            for (int r = 0; r < 4; ++r) {
                const int m = mt * 16 + quad * 4 + r;
                const float z  = tanh_fast(acc[j][mt][r] + b2);
                const float zd = (1.f - z * z) * acc[j][mt + 2][r];
                bufA[m * SO + n]        = f2b(z);
                bufA[(m + 32) * SO + n] = f2b(zd);
            }
        }
    }
    __syncthreads();

    {
        const int p = tid >> 3, s = tid & 7;
        float yv = 0.f, jv = 0.f;
        #pragma unroll
        for (int i = 0; i < 16; ++i) {
            const int n = s + i * 8;
            const float w = d_w3[n];
            yv += b2f(bufA[p * SO + n]) * w;
            jv += b2f(bufA[(p + 32) * SO + n]) * w;
        }
        #pragma unroll
        for (int off = 4; off > 0; off >>= 1) {
            yv += __shfl_down(yv, off, 8);
            jv += __shfl_down(jv, off, 8);
        }
        if (s == 0) {
            out[p0 + p]      = yv + d_b3[0];
            out[kP + p0 + p] = jv;
        }
    }
}

extern "C" void kernel_launch(void* const* d_in, const int* in_sizes, int n_in,
                              void* d_out, int out_size, void* d_ws, size_t ws_size,
                              hipStream_t stream)
{
    typedef const float* fp;
    fp t    = (fp)d_in[0];
    fp x    = (fp)d_in[1];
    fp q_w0 = (fp)d_in[2],  q_b0 = (fp)d_in[3];
    fp k_w0 = (fp)d_in[4],  k_b0 = (fp)d_in[5];
    fp v_w0 = (fp)d_in[6],  v_b0 = (fp)d_in[7];
    fp q_w1 = (fp)d_in[8],  q_b1 = (fp)d_in[9];
    fp k_w1 = (fp)d_in[10], k_b1 = (fp)d_in[11];
    fp v_w1 = (fp)d_in[12], v_b1 = (fp)d_in[13];
    fp q_w2 = (fp)d_in[14], q_b2 = (fp)d_in[15];
    fp k_w2 = (fp)d_in[16], k_b2 = (fp)d_in[17];
    fp v_w2 = (fp)d_in[18], v_b2 = (fp)d_in[19];
    fp p_w  = (fp)d_in[20], p_b  = (fp)d_in[21];
    fp d_w0 = (fp)d_in[22], d_b0 = (fp)d_in[23];
    fp d_w1 = (fp)d_in[24], d_b1 = (fp)d_in[25];
    fp d_w2 = (fp)d_in[26], d_b2 = (fp)d_in[27];
    fp d_w3 = (fp)d_in[28], d_b3 = (fp)d_in[29];

    float* obuf = (float*)d_ws;                                  // 32768*128 fp32
    __hip_bfloat16* wsb  = (__hip_bfloat16*)(obuf + (size_t)kP * kH);
    __hip_bfloat16* kbuf = wsb;                                  // 2048*128
    __hip_bfloat16* vbuf = kbuf + (size_t)kBN * kH;              // 2048*128
    __hip_bfloat16* qbuf = vbuf + (size_t)kBN * kH;              // 2048*2048
    __hip_bfloat16* pwf  = qbuf + (size_t)kBN * kD * kH;         // 8192
    __hip_bfloat16* w0f  = pwf + 8192;                           // 16384
    __hip_bfloat16* w1f  = w0f + 16384;                          // 65536
    __hip_bfloat16* w2f  = w1f + 65536;                          // 32768
    __hip_bfloat16* k0f  = w2f + 32768;                          // 8192
    __hip_bfloat16* v0f  = k0f + 8192;                           // 8192
    __hip_bfloat16* q0f  = v0f + 8192;                           // 8192
    __hip_bfloat16* k1f  = q0f + 8192;                           // 65536
    __hip_bfloat16* v1f  = k1f + 65536;                          // 65536
    __hip_bfloat16* q1f  = v1f + 65536;                          // 65536
    __hip_bfloat16* k2f  = q1f + 65536;                          // 32768
    __hip_bfloat16* v2f  = k2f + 32768;                          // 32768
    __hip_bfloat16* q2f  = v2f + 32768;                          // 524288
    __hip_bfloat16* h1q  = q2f + 524288;                         // 2048*256

    float* out = (float*)d_out;

    prep_frag<<<456, 256, 0, stream>>>(p_w, d_w0, d_w1, d_w2,
        k_w0, k_w1, k_w2, v_w0, v_w1, v_w2, q_w0, q_w1, q_w2,
        pwf, w0f, w1f, w2f, k0f, k1f, k2f, v0f, v1f, v2f, q0f, q1f, q2f);
    mlp_kernel<<<kBN / 32, 256, 0, stream>>>(x,
        k_b0, k_b1, k_b2, v_b0, v_b1, v_b2, q_b0, q_b1,
        k0f, k1f, k2f, v0f, v1f, v2f, q0f, q1f, kbuf, vbuf, h1q);
    qgemm_kernel<<<(kBN / 32) * 8, 256, 0, stream>>>(q_b2, h1q, q2f, qbuf);
    attn_kernel<<<kB * kD * 4, 256, 0, stream>>>(qbuf, kbuf, vbuf, obuf);
    dim_kernel<<<kP / 32, 256, 0, stream>>>(t, x, p_b, d_w0, d_b0, d_b1, d_b2, d_w3, d_b3,
        pwf, w0f, w1f, w2f, obuf, out);
}